// Round 1
// baseline (886.299 us; speedup 1.0000x reference)
//
#include <hip/hip_runtime.h>

#define B_  16
#define CIN 128
#define C_  256
#define HW  4096
#define EPSF 1e-8f

// ---------------- repack w1 [256][128][3][3] -> w1p [128*9][256] ----------------
__global__ __launch_bounds__(256) void k_repack(const float* __restrict__ w1,
                                                float* __restrict__ w1p) {
    int idx = blockIdx.x * 256 + threadIdx.x;          // over 128*9*256 = 294912
    int oc = idx & 255, rest = idx >> 8;               // rest = cin*9 + k
    w1p[idx] = w1[oc * 1152 + rest];
}

// ---------------- conv1: 3x3 SAME conv, f32, + b1 ----------------
// grid 4096: b(16) x h(64) x octile(4).  block 256: lane w (64) x wave->16 oc.
__global__ __launch_bounds__(256) void k_conv1(const float* __restrict__ x,
                                               const float* __restrict__ w1p,
                                               const float* __restrict__ b1,
                                               float* __restrict__ conv1) {
    __shared__ float xs[64][3][66];
    const int bx = blockIdx.x;
    const int ot = bx & 3;
    const int h  = (bx >> 2) & 63;
    const int b  = bx >> 8;
    const int tid = threadIdx.x;
    const int w   = tid & 63;
    const int wv  = __builtin_amdgcn_readfirstlane(tid >> 6);
    const int ocb = ot * 64 + wv * 16;

    float acc[16];
#pragma unroll
    for (int i = 0; i < 16; i++) acc[i] = 0.f;

    for (int cc = 0; cc < 2; ++cc) {
        const int c0 = cc * 64;
        __syncthreads();
        // stage 64 cin x 3 rows x 64 cols (+zero halo)
#pragma unroll 4
        for (int k = 0; k < 48; k++) {
            int fi = tid + k * 256;
            int row = fi >> 6, col = fi & 63;
            int ci = row / 3, dh = row - ci * 3;
            int gh = h + dh - 1;
            float v = 0.f;
            if ((unsigned)gh < 64u)
                v = x[((b * CIN + c0 + ci) << 12) + (gh << 6) + col];
            xs[ci][dh][col + 1] = v;
        }
        if (tid < 192) { int ci = tid / 3, dh = tid - (tid / 3) * 3;
                         xs[ci][dh][0] = 0.f; xs[ci][dh][65] = 0.f; }
        __syncthreads();

        for (int ci = 0; ci < 64; ++ci) {
            const int cin = c0 + ci;
            const float* wbase = w1p + ((cin * 9) << 8) + ocb;   // wave-uniform
#pragma unroll
            for (int kh = 0; kh < 3; ++kh) {
                float xv0 = xs[ci][kh][w];
                float xv1 = xs[ci][kh][w + 1];
                float xv2 = xs[ci][kh][w + 2];
#pragma unroll
                for (int kw = 0; kw < 3; ++kw) {
                    float xv = (kw == 0) ? xv0 : ((kw == 1) ? xv1 : xv2);
                    const float4* wp = (const float4*)(wbase + ((kh * 3 + kw) << 8));
                    float4 wa = wp[0], wb = wp[1], wc = wp[2], wd = wp[3];
                    acc[0]  += wa.x * xv; acc[1]  += wa.y * xv; acc[2]  += wa.z * xv; acc[3]  += wa.w * xv;
                    acc[4]  += wb.x * xv; acc[5]  += wb.y * xv; acc[6]  += wb.z * xv; acc[7]  += wb.w * xv;
                    acc[8]  += wc.x * xv; acc[9]  += wc.y * xv; acc[10] += wc.z * xv; acc[11] += wc.w * xv;
                    acc[12] += wd.x * xv; acc[13] += wd.y * xv; acc[14] += wd.z * xv; acc[15] += wd.w * xv;
                }
            }
        }
    }
#pragma unroll
    for (int i = 0; i < 16; i++) {
        int oc = ocb + i;
        conv1[((b * C_ + oc) << 12) + (h << 6) + w] = acc[i] + b1[oc];
    }
}

// ---------------- gap1: mean over HW per (b,c) ----------------
__global__ __launch_bounds__(256) void k_gap(const float* __restrict__ conv1,
                                             float* __restrict__ gap1) {
    int bc = blockIdx.x, tid = threadIdx.x;
    const float4* p = (const float4*)(conv1 + ((long)bc << 12));
    float s = 0.f;
#pragma unroll
    for (int k = 0; k < 4; k++) { float4 v = p[tid + k * 256]; s += v.x + v.y + v.z + v.w; }
    for (int off = 32; off; off >>= 1) s += __shfl_down(s, off);
    __shared__ float red[4];
    if ((tid & 63) == 0) red[tid >> 6] = s;
    __syncthreads();
    if (tid == 0) gap1[bc] = (red[0] + red[1] + red[2] + red[3]) * (1.f / 4096.f);
}

// ---------------- tiny MLP chain + derived scalars ----------------
// c2 = gap1@w2.T + b2 ; c3 = c2@w3.T + b3 ; scale = 1+c3 ; ga = gap1*scale^2 ; n_g
__global__ __launch_bounds__(256) void k_mlp(const float* __restrict__ gap1,
                                             const float* __restrict__ w2, const float* __restrict__ b2,
                                             const float* __restrict__ w3, const float* __restrict__ b3,
                                             float* __restrict__ scale, float* __restrict__ ga,
                                             float* __restrict__ n_g) {
    int b = blockIdx.x, tid = threadIdx.x;
    __shared__ float gs[256], c2s[256], red[4];
    gs[tid] = gap1[b * 256 + tid];
    __syncthreads();
    {
        const float4* wr = (const float4*)(w2 + tid * 256);
        float a = b2[tid];
#pragma unroll 8
        for (int c4 = 0; c4 < 64; c4++) {
            float4 wv = wr[c4];
            a += wv.x * gs[c4*4] + wv.y * gs[c4*4+1] + wv.z * gs[c4*4+2] + wv.w * gs[c4*4+3];
        }
        c2s[tid] = a;
    }
    __syncthreads();
    float a3 = b3[tid];
    {
        const float4* wr = (const float4*)(w3 + tid * 256);
#pragma unroll 8
        for (int c4 = 0; c4 < 64; c4++) {
            float4 wv = wr[c4];
            a3 += wv.x * c2s[c4*4] + wv.y * c2s[c4*4+1] + wv.z * c2s[c4*4+2] + wv.w * c2s[c4*4+3];
        }
    }
    float s1 = 1.f + a3;
    float g2 = gs[tid] * s1;
    scale[b * 256 + tid] = s1;
    ga[b * 256 + tid] = g2 * s1;
    float r = g2 * g2;
    for (int off = 32; off; off >>= 1) r += __shfl_down(r, off);
    if ((tid & 63) == 0) red[tid >> 6] = r;
    __syncthreads();
    if (tid == 0) n_g[b] = fmaxf(sqrtf(red[0] + red[1] + red[2] + red[3]), EPSF);
}

// ---------------- cos -> r1[b][p] ----------------
__global__ __launch_bounds__(256) void k_cos(const float* __restrict__ conv1,
                                             const float* __restrict__ scale,
                                             const float* __restrict__ ga,
                                             const float* __restrict__ n_g,
                                             float* __restrict__ r1) {
    int bx = blockIdx.x; int b = bx >> 4, pt = bx & 15;
    int tid = threadIdx.x; int p = pt * 256 + tid;
    __shared__ float ss[256], gg[256];
    ss[tid] = scale[b * 256 + tid];
    gg[tid] = ga[b * 256 + tid];
    __syncthreads();
    const float* base = conv1 + ((long)b << 20) + p;
    float num = 0.f, den = 0.f;
#pragma unroll 16
    for (int c = 0; c < 256; c++) {
        float v = base[(long)c << 12];
        num += gg[c] * v;
        float sv = ss[c] * v;
        den += sv * sv;
    }
    float na = fmaxf(sqrtf(den), EPSF);
    r1[b * 4096 + p] = num / (n_g[b] * na);
}

// ---------------- conv4 (1x1, channel-scaled) written NHWC into d_out ----------------
// out[b][p][o] = sum_c w4[o][c]*scale[b][c]*conv1[b][c][p] + b4[o]
// grid 4096: b(16) x ptile(64) x otile(4). block 256: to=tid&15 (4 o), tp=tid>>4 (4 p).
__global__ __launch_bounds__(256) void k_conv4(const float* __restrict__ conv1,
                                               const float* __restrict__ w4,
                                               const float* __restrict__ b4,
                                               const float* __restrict__ scale,
                                               float* __restrict__ outb) {
    __shared__ float as_[32][64];
    __shared__ float bs_[32][64];
    __shared__ float ssc[256];
    int bx = blockIdx.x;
    int ot = bx & 3, pt = (bx >> 2) & 63, b = bx >> 8;
    int tid = threadIdx.x;
    int to = tid & 15, tp = tid >> 4;
    int p0 = pt * 64;
    ssc[tid] = scale[b * 256 + tid];
    float acc[4][4];
#pragma unroll
    for (int i = 0; i < 4; i++)
#pragma unroll
        for (int j = 0; j < 4; j++) acc[i][j] = 0.f;

    for (int k = 0; k < 8; k++) {
        int c0 = k * 32;
        __syncthreads();
#pragma unroll
        for (int q = 0; q < 2; q++) {           // stage conv1 tile [32c][64p]
            int f4i = tid + q * 256;
            int row = f4i >> 4, col = f4i & 15;
            float4 v = *(const float4*)(conv1 + ((long)b << 20) + ((long)(c0 + row) << 12) + p0 + col * 4);
            *(float4*)&as_[row][col * 4] = v;
        }
#pragma unroll
        for (int q = 0; q < 2; q++) {           // stage w4 tile [32c][64o] (transposed)
            int o = tid & 63, cq = (tid >> 6) + q * 4;
            float4 wv = *(const float4*)(w4 + ((ot * 64 + o) << 8) + c0 + cq * 4);
            bs_[cq * 4 + 0][o] = wv.x; bs_[cq * 4 + 1][o] = wv.y;
            bs_[cq * 4 + 2][o] = wv.z; bs_[cq * 4 + 3][o] = wv.w;
        }
        __syncthreads();
#pragma unroll 8
        for (int c = 0; c < 32; c++) {
            float4 a4  = *(const float4*)&as_[c][tp * 4];
            float4 b4v = *(const float4*)&bs_[c][to * 4];
            float sc = ssc[c0 + c];
            float bb0 = b4v.x * sc, bb1 = b4v.y * sc, bb2 = b4v.z * sc, bb3 = b4v.w * sc;
            acc[0][0] += a4.x * bb0; acc[0][1] += a4.x * bb1; acc[0][2] += a4.x * bb2; acc[0][3] += a4.x * bb3;
            acc[1][0] += a4.y * bb0; acc[1][1] += a4.y * bb1; acc[1][2] += a4.y * bb2; acc[1][3] += a4.y * bb3;
            acc[2][0] += a4.z * bb0; acc[2][1] += a4.z * bb1; acc[2][2] += a4.z * bb2; acc[2][3] += a4.z * bb3;
            acc[3][0] += a4.w * bb0; acc[3][1] += a4.w * bb1; acc[3][2] += a4.w * bb2; acc[3][3] += a4.w * bb3;
        }
    }
    float4 bias = *(const float4*)(b4 + ot * 64 + to * 4);
    float bv[4] = {bias.x, bias.y, bias.z, bias.w};
#pragma unroll
    for (int pi = 0; pi < 4; pi++) {
        float4 o4;
        o4.x = acc[pi][0] + bv[0]; o4.y = acc[pi][1] + bv[1];
        o4.z = acc[pi][2] + bv[2]; o4.w = acc[pi][3] + bv[3];
        *(float4*)(outb + ((long)b << 20) + ((long)(p0 + tp * 4 + pi) << 8) + ot * 64 + to * 4) = o4;
    }
}

// ---------------- t[b][i][b'] = sum_j r2[b][i][j] * r1[b'][j] ----------------
// grid 256: b(16) x itile(16, 16 i each). block 256: il=tid>>4, bp=tid&15.
__global__ __launch_bounds__(256) void k_t(const float* __restrict__ outb,
                                           const float* __restrict__ r1,
                                           float* __restrict__ tmat) {
    __shared__ float r2c[16][256];
    __shared__ float r1c[16][260];
    int bx = blockIdx.x; int b = bx >> 4, it = bx & 15;
    int tid = threadIdx.x;
    int il = tid >> 4, bp = tid & 15;
    float acc = 0.f;
    for (int jc = 0; jc < 4096; jc += 256) {
        __syncthreads();
#pragma unroll
        for (int k = 0; k < 4; k++) {
            int f4i = tid + k * 256;
            int row = f4i >> 6, col = f4i & 63;
            *(float4*)&r2c[row][col * 4] =
                *(const float4*)(outb + ((long)b << 20) + ((long)(it * 16 + row) << 12) + jc + col * 4);
            *(float4*)&r1c[row][col * 4] =
                *(const float4*)(r1 + ((long)row << 12) + jc + col * 4);
        }
        __syncthreads();
#pragma unroll 8
        for (int j = 0; j < 256; j += 4) {
            float4 a4  = *(const float4*)&r2c[il][j];
            float4 b4v = *(const float4*)&r1c[bp][j];
            acc += a4.x * b4v.x + a4.y * b4v.y + a4.z * b4v.z + a4.w * b4v.w;
        }
    }
    tmat[((b * 256) + it * 16 + il) * 16 + bp] = acc;
}

// ---------------- m2[b][i][p] = sum_b' t[b][i][b'] * r1[b'][p]  (overwrites d_out) ----------------
// grid 2048: b(16) x itile(16) x pchunk(8 of 512). block 256.
__global__ __launch_bounds__(256) void k_m2(const float* __restrict__ tmat,
                                            const float* __restrict__ r1,
                                            float* __restrict__ outb) {
    __shared__ float r1s[16][512];
    __shared__ float ts[256];
    int bx = blockIdx.x;
    int b = bx >> 7, it = (bx >> 3) & 15, pc = bx & 7;
    int tid = threadIdx.x;
    ts[tid] = tmat[(b * 256 + it * 16) * 16 + tid];
#pragma unroll
    for (int k = 0; k < 8; k++) {
        int f4i = tid + k * 256;
        int row = f4i >> 7, col = f4i & 127;
        *(float4*)&r1s[row][col * 4] = *(const float4*)(r1 + ((long)row << 12) + pc * 512 + col * 4);
    }
    __syncthreads();
    for (int il = 0; il < 16; il++) {
        float tv[16];
#pragma unroll
        for (int bp = 0; bp < 16; bp++) tv[bp] = ts[il * 16 + bp];
#pragma unroll
        for (int k = 0; k < 2; k++) {
            int p = k * 256 + tid;
            float s = 0.f;
#pragma unroll
            for (int bp = 0; bp < 16; bp++) s += tv[bp] * r1s[bp][p];
            outb[((long)b << 20) + ((long)(it * 16 + il) << 12) + pc * 512 + p] = s;
        }
    }
}

extern "C" void kernel_launch(void* const* d_in, const int* in_sizes, int n_in,
                              void* d_out, int out_size, void* d_ws, size_t ws_size,
                              hipStream_t stream) {
    const float* x  = (const float*)d_in[0];
    const float* w1 = (const float*)d_in[1];
    const float* b1 = (const float*)d_in[2];
    const float* w2 = (const float*)d_in[3];
    const float* b2 = (const float*)d_in[4];
    const float* w3 = (const float*)d_in[5];
    const float* b3 = (const float*)d_in[6];
    const float* w4 = (const float*)d_in[7];
    const float* b4 = (const float*)d_in[8];
    float* out = (float*)d_out;
    float* ws  = (float*)d_ws;

    float* conv1 = ws;                       // 16,777,216 f
    float* w1p   = conv1 + 16777216;         // 294,912 f
    float* gap1  = w1p + 294912;             // 4096
    float* scale = gap1 + 4096;              // 4096
    float* ga    = scale + 4096;             // 4096
    float* n_g   = ga + 4096;                // 16
    float* r1    = n_g + 16;                 // 65,536
    float* tmat  = r1 + 65536;               // 65,536

    k_repack<<<1152, 256, 0, stream>>>(w1, w1p);
    k_conv1 <<<4096, 256, 0, stream>>>(x, w1p, b1, conv1);
    k_gap   <<<4096, 256, 0, stream>>>(conv1, gap1);
    k_mlp   <<<16,   256, 0, stream>>>(gap1, w2, b2, w3, b3, scale, ga, n_g);
    k_cos   <<<256,  256, 0, stream>>>(conv1, scale, ga, n_g, r1);
    k_conv4 <<<4096, 256, 0, stream>>>(conv1, w4, b4, scale, out);
    k_t     <<<256,  256, 0, stream>>>(out, r1, tmat);
    k_m2    <<<2048, 256, 0, stream>>>(tmat, r1, out);
}

// Round 2
// 339.092 us; speedup vs baseline: 2.6137x; 2.6137x over previous
//
#include <hip/hip_runtime.h>

#define EPSF 1e-8f

typedef __attribute__((ext_vector_type(8))) short bf16x8;
typedef __attribute__((ext_vector_type(4))) float f32x4;

#define MFMA(a, b, c) __builtin_amdgcn_mfma_f32_16x16x32_bf16(a, b, c, 0, 0, 0)

// split f32 into (hi bf16 | lo bf16) packed in one u32: low16 = hi-part, high16 = lo-part
__device__ __forceinline__ uint32_t splitpack(float v) {
    uint32_t u = __float_as_uint(v);
    uint32_t hb = (u + 0x7fffu + ((u >> 16) & 1u)) & 0xffff0000u;  // RNE bf16 of v, as f32 bits
    float rem = v - __uint_as_float(hb);
    uint32_t r = __float_as_uint(rem);
    uint32_t lb = (r + 0x7fffu + ((r >> 16) & 1u)) >> 16;          // RNE bf16 of remainder
    return (hb >> 16) | (lb << 16);
}
__device__ __forceinline__ float bf_lo(uint32_t u) { return __uint_as_float(u << 16); }
__device__ __forceinline__ float bf_hi(uint32_t u) { return __uint_as_float(u & 0xffff0000u); }

// read 8 (hi|lo)-packed u32 from LDS (two b128) and split into hi/lo bf16x8 fragments
__device__ __forceinline__ void unpack_frag(const uint32_t* xs, int idx0, int idx1,
                                            bf16x8& hi, bf16x8& lo) {
    uint4 a = *(const uint4*)(xs + idx0);
    uint4 b = *(const uint4*)(xs + idx1);
    union { uint32_t w[4]; bf16x8 v; } H, L;
    H.w[0] = (a.x & 0xffffu) | (a.y << 16);
    H.w[1] = (a.z & 0xffffu) | (a.w << 16);
    H.w[2] = (b.x & 0xffffu) | (b.y << 16);
    H.w[3] = (b.z & 0xffffu) | (b.w << 16);
    L.w[0] = (a.x >> 16) | (a.y & 0xffff0000u);
    L.w[1] = (a.z >> 16) | (a.w & 0xffff0000u);
    L.w[2] = (b.x >> 16) | (b.y & 0xffff0000u);
    L.w[3] = (b.z >> 16) | (b.w & 0xffff0000u);
    hi = H.v; lo = L.v;
}

// ---------- pack w1 [256][128][3][3] into MFMA B-fragment order, hi/lo bf16 ----------
// layout: [tap 9][ch 4][nt 16][kg 4][oc16 16][j 8] ; frag load = base + lane*8 shorts
__global__ __launch_bounds__(256) void k_wpack(const float* __restrict__ w1,
                                               short* __restrict__ Bh, short* __restrict__ Bl) {
    int d = blockIdx.x * 256 + threadIdx.x;          // 294912
    int j = d & 7, oc16 = (d >> 3) & 15, kg = (d >> 7) & 3, nt = (d >> 9) & 15;
    int ch = (d >> 13) & 3, tap = d >> 15;
    int cin = ch * 32 + kg * 8 + j;
    int oc = nt * 16 + oc16;
    uint32_t u = splitpack(w1[oc * 1152 + cin * 9 + tap]);
    Bh[d] = (short)(u & 0xffffu);
    Bl[d] = (short)(u >> 16);
}

// ---------- pack w4 [256][256] into B-fragment order: [ch 8][nt 16][kg 4][o16 16][j 8] ----------
__global__ __launch_bounds__(256) void k_w4pack(const float* __restrict__ w4,
                                                short* __restrict__ Bh, short* __restrict__ Bl) {
    int d = blockIdx.x * 256 + threadIdx.x;          // 65536
    int j = d & 7, o16 = (d >> 3) & 15, kg = (d >> 7) & 3, nt = (d >> 9) & 15;
    int ch = (d >> 13) & 7;
    int c = ch * 32 + kg * 8 + j;
    int o = nt * 16 + o16;
    uint32_t u = splitpack(w4[o * 256 + c]);
    Bh[d] = (short)(u & 0xffffu);
    Bl[d] = (short)(u >> 16);
}

// ---------- conv1: 3x3 SAME via 9-tap implicit GEMM, bf16x3 MFMA ----------
// block: 128 pixels (2 h-rows x 64 w) x 256 oc. 4 waves (2M x 2N), wave = 64p x 128oc.
// output: hi/lo bf16 planes NHWC [b][p][c]; gap partials fused.
__global__ __launch_bounds__(256, 2) void k_conv1(
        const float* __restrict__ x, const short* __restrict__ Bph,
        const short* __restrict__ Bpl, const float* __restrict__ b1,
        unsigned short* __restrict__ c1h, unsigned short* __restrict__ c1l,
        float* __restrict__ gpart) {
    __shared__ uint32_t xs[4 * 66 * 32];
    const int bx = blockIdx.x;
    const int hp = bx & 31, b = bx >> 5;
    const int tid = threadIdx.x;
    const int lane = tid & 63, wv = tid >> 6;
    const int mhalf = wv >> 1, nhalf = wv & 1;
    const int l15 = lane & 15, kg = lane >> 4;
    const int h0 = hp * 2;

    {   // zero the w-halo slots (wl = 0 and 65) once; never rewritten
        int r = tid >> 6, sl = ((tid >> 5) & 1) ? 65 : 0, pos = tid & 31;
        xs[(r * 66 + sl) * 32 + pos] = 0u;
    }

    const int sw = tid & 63, sr = tid >> 6;
    const int gh = h0 - 1 + sr;
    const bool vrow = ((unsigned)gh) < 64u;
    const float* xrow = x + ((long)b << 19) + ((long)gh << 6) + sw;

    float xr[32];
#pragma unroll
    for (int ci = 0; ci < 32; ++ci) xr[ci] = vrow ? xrow[ci << 12] : 0.f;

    f32x4 acc[4][8];
#pragma unroll
    for (int i = 0; i < 4; ++i)
#pragma unroll
        for (int j = 0; j < 8; ++j) acc[i][j] = (f32x4){0.f, 0.f, 0.f, 0.f};

    const int wl_s = sw + 1;
    const int wbase = (sr * 66 + wl_s) * 32;
    const int swz_s = (wl_s & 7) << 2;

    for (int ch = 0; ch < 4; ++ch) {
        __syncthreads();
#pragma unroll
        for (int ci = 0; ci < 32; ++ci) xs[wbase + (ci ^ swz_s)] = splitpack(xr[ci]);
        __syncthreads();
        if (ch < 3) {
            const float* xn = xrow + ((long)(ch + 1) << 17);
#pragma unroll
            for (int ci = 0; ci < 32; ++ci) xr[ci] = vrow ? xn[ci << 12] : 0.f;
        }
#pragma unroll
        for (int kh = 0; kh < 3; ++kh) {
#pragma unroll
            for (int kw = 0; kw < 3; ++kw) {
                const int tap = kh * 3 + kw;
                bf16x8 ah[4], al[4];
#pragma unroll
                for (int mt = 0; mt < 4; ++mt) {
                    const int wl = kw + mt * 16 + l15;
                    const int rb = ((mhalf + kh) * 66 + wl) * 32;
                    const int s = wl & 7;
                    unpack_frag(xs, rb + (((kg * 2) ^ s) << 2),
                                rb + (((kg * 2 + 1) ^ s) << 2), ah[mt], al[mt]);
                }
                const int fb = (tap * 4 + ch) * 16;
#pragma unroll
                for (int nt = 0; nt < 8; ++nt) {
                    const int ntg = nhalf * 8 + nt;
                    const bf16x8 bh = *(const bf16x8*)(Bph + (fb + ntg) * 512 + lane * 8);
                    const bf16x8 bl = *(const bf16x8*)(Bpl + (fb + ntg) * 512 + lane * 8);
#pragma unroll
                    for (int mt = 0; mt < 4; ++mt) {
                        acc[mt][nt] = MFMA(ah[mt], bh, acc[mt][nt]);
                        acc[mt][nt] = MFMA(ah[mt], bl, acc[mt][nt]);
                        acc[mt][nt] = MFMA(al[mt], bh, acc[mt][nt]);
                    }
                }
            }
        }
    }

    const int hrow = h0 + mhalf;
#pragma unroll
    for (int nt = 0; nt < 8; ++nt) {
        const int oc = nhalf * 128 + nt * 16 + l15;
        float s = 0.f;
#pragma unroll
        for (int mt = 0; mt < 4; ++mt)
#pragma unroll
            for (int rg = 0; rg < 4; ++rg) s += acc[mt][nt][rg];
        s += __shfl_xor(s, 16);
        s += __shfl_xor(s, 32);
        if (kg == 0) gpart[((b * 32 + hp) * 2 + mhalf) * 256 + oc] = s;

        const float bias = b1[oc];
#pragma unroll
        for (int mt = 0; mt < 4; ++mt) {
#pragma unroll
            for (int rg = 0; rg < 4; ++rg) {
                const int p = hrow * 64 + mt * 16 + kg * 4 + rg;
                const uint32_t u = splitpack(acc[mt][nt][rg] + bias);
                const long idx = ((long)b << 20) + (long)p * 256 + oc;
                c1h[idx] = (unsigned short)(u & 0xffffu);
                c1l[idx] = (unsigned short)(u >> 16);
            }
        }
    }
}

// ---------- tiny MLP chain: sum gap partials, c2, c3 -> scale, ga, n_g ----------
__global__ __launch_bounds__(256) void k_mlp(const float* __restrict__ gpart,
                                             const float* __restrict__ b1,
                                             const float* __restrict__ w2, const float* __restrict__ b2,
                                             const float* __restrict__ w3, const float* __restrict__ b3,
                                             float* __restrict__ scale, float* __restrict__ ga,
                                             float* __restrict__ n_g) {
    int b = blockIdx.x, tid = threadIdx.x;
    __shared__ float gs[256], c2s[256], red[4];
    float g = 0.f;
#pragma unroll 8
    for (int i = 0; i < 64; ++i) g += gpart[(b * 64 + i) * 256 + tid];
    gs[tid] = g * (1.f / 4096.f) + b1[tid];
    __syncthreads();
    {
        const float4* wr = (const float4*)(w2 + tid * 256);
        float a = b2[tid];
#pragma unroll 8
        for (int c4 = 0; c4 < 64; c4++) {
            float4 wv = wr[c4];
            a += wv.x * gs[c4*4] + wv.y * gs[c4*4+1] + wv.z * gs[c4*4+2] + wv.w * gs[c4*4+3];
        }
        c2s[tid] = a;
    }
    __syncthreads();
    float a3 = b3[tid];
    {
        const float4* wr = (const float4*)(w3 + tid * 256);
#pragma unroll 8
        for (int c4 = 0; c4 < 64; c4++) {
            float4 wv = wr[c4];
            a3 += wv.x * c2s[c4*4] + wv.y * c2s[c4*4+1] + wv.z * c2s[c4*4+2] + wv.w * c2s[c4*4+3];
        }
    }
    float s1 = 1.f + a3;
    float g2 = gs[tid] * s1;
    scale[b * 256 + tid] = s1;
    ga[b * 256 + tid] = g2 * s1;
    float r = g2 * g2;
    for (int off = 32; off; off >>= 1) r += __shfl_down(r, off);
    if ((tid & 63) == 0) red[tid >> 6] = r;
    __syncthreads();
    if (tid == 0) n_g[b] = fmaxf(sqrtf(red[0] + red[1] + red[2] + red[3]), EPSF);
}

// ---------- cos -> r1[b][p], NHWC reads, 32-lane reduce per pixel ----------
__global__ __launch_bounds__(256) void k_cos(
        const unsigned short* __restrict__ c1h, const unsigned short* __restrict__ c1l,
        const float* __restrict__ scale, const float* __restrict__ ga,
        const float* __restrict__ n_g, float* __restrict__ r1) {
    const int bx = blockIdx.x;
    const int pt = bx & 63, b = bx >> 6;
    const int tid = threadIdx.x;
    const int lane = tid & 63, wv = tid >> 6;
    const int half = lane >> 5, l31 = lane & 31;
    const float4 fa0 = *(const float4*)(ga + b * 256 + l31 * 8);
    const float4 fa1 = *(const float4*)(ga + b * 256 + l31 * 8 + 4);
    const float4 fs0 = *(const float4*)(scale + b * 256 + l31 * 8);
    const float4 fs1 = *(const float4*)(scale + b * 256 + l31 * 8 + 4);
    const float ga8[8] = {fa0.x, fa0.y, fa0.z, fa0.w, fa1.x, fa1.y, fa1.z, fa1.w};
    const float sc8[8] = {fs0.x, fs0.y, fs0.z, fs0.w, fs1.x, fs1.y, fs1.z, fs1.w};
    const float ng = n_g[b];
#pragma unroll
    for (int pp = 0; pp < 8; ++pp) {
        const int p = pt * 64 + wv * 16 + pp * 2 + half;
        const long base = ((long)b << 20) + (long)p * 256 + l31 * 8;
        uint4 h4 = *(const uint4*)(c1h + base);
        uint4 l4 = *(const uint4*)(c1l + base);
        uint32_t hw[4] = {h4.x, h4.y, h4.z, h4.w};
        uint32_t lw[4] = {l4.x, l4.y, l4.z, l4.w};
        float num = 0.f, den = 0.f;
#pragma unroll
        for (int q = 0; q < 4; ++q) {
            float v0 = bf_lo(hw[q]) + bf_lo(lw[q]);
            float v1 = bf_hi(hw[q]) + bf_hi(lw[q]);
            num += ga8[q * 2] * v0 + ga8[q * 2 + 1] * v1;
            float t0 = sc8[q * 2] * v0, t1 = sc8[q * 2 + 1] * v1;
            den += t0 * t0 + t1 * t1;
        }
#pragma unroll
        for (int off = 1; off <= 16; off <<= 1) {
            num += __shfl_xor(num, off);
            den += __shfl_xor(den, off);
        }
        if (l31 == 0) {
            float na = fmaxf(sqrtf(den), EPSF);
            r1[b * 4096 + p] = num / (ng * na);
        }
    }
}

// ---------- conv4: out[b][p][o] = sum_c w4[o][c]*scale[c]*conv1[b][p][c] + b4 (MFMA, NHWC f32 out) ----------
__global__ __launch_bounds__(256, 2) void k_conv4(
        const unsigned short* __restrict__ c1h, const unsigned short* __restrict__ c1l,
        const short* __restrict__ B4h, const short* __restrict__ B4l,
        const float* __restrict__ scale, const float* __restrict__ b4,
        float* __restrict__ outb) {
    __shared__ uint32_t as_[128 * 32];
    __shared__ float ssc[256];
    const int bx = blockIdx.x;
    const int pt = bx & 31, b = bx >> 5;
    const int tid = threadIdx.x;
    const int lane = tid & 63, wv = tid >> 6;
    const int mhalf = wv >> 1, nhalf = wv & 1;
    const int l15 = lane & 15, kg = lane >> 4;
    const int p0 = pt * 128;

    ssc[tid] = scale[b * 256 + tid];

    const int sp = tid & 127, sg = tid >> 7;
    const long cbase = ((long)b << 20) + (long)(p0 + sp) * 256;
    const int swz = (sp & 7) << 2;

    uint4 ph[2], pl[2];
#pragma unroll
    for (int g = 0; g < 2; ++g) {
        const int c8 = (sg * 2 + g) * 8;
        ph[g] = *(const uint4*)(c1h + cbase + c8);
        pl[g] = *(const uint4*)(c1l + cbase + c8);
    }

    f32x4 acc[4][8];
#pragma unroll
    for (int i = 0; i < 4; ++i)
#pragma unroll
        for (int j = 0; j < 8; ++j) acc[i][j] = (f32x4){0.f, 0.f, 0.f, 0.f};

    for (int ch = 0; ch < 8; ++ch) {
        __syncthreads();
#pragma unroll
        for (int g = 0; g < 2; ++g) {
            const int ci0 = (sg * 2 + g) * 8;
            uint32_t hw[4] = {ph[g].x, ph[g].y, ph[g].z, ph[g].w};
            uint32_t lw[4] = {pl[g].x, pl[g].y, pl[g].z, pl[g].w};
#pragma unroll
            for (int q = 0; q < 4; ++q) {
                const int cc = ch * 32 + ci0 + q * 2;
                float v0 = (bf_lo(hw[q]) + bf_lo(lw[q])) * ssc[cc];
                float v1 = (bf_hi(hw[q]) + bf_hi(lw[q])) * ssc[cc + 1];
                as_[sp * 32 + ((ci0 + q * 2) ^ swz)]     = splitpack(v0);
                as_[sp * 32 + ((ci0 + q * 2 + 1) ^ swz)] = splitpack(v1);
            }
        }
        __syncthreads();
        if (ch < 7) {
#pragma unroll
            for (int g = 0; g < 2; ++g) {
                const int c8 = (ch + 1) * 32 + (sg * 2 + g) * 8;
                ph[g] = *(const uint4*)(c1h + cbase + c8);
                pl[g] = *(const uint4*)(c1l + cbase + c8);
            }
        }
        bf16x8 ah[4], al[4];
#pragma unroll
        for (int mt = 0; mt < 4; ++mt) {
            const int row = mhalf * 64 + mt * 16 + l15;
            const int rb = row * 32;
            const int s = row & 7;
            unpack_frag(as_, rb + (((kg * 2) ^ s) << 2),
                        rb + (((kg * 2 + 1) ^ s) << 2), ah[mt], al[mt]);
        }
#pragma unroll
        for (int nt = 0; nt < 8; ++nt) {
            const int ntg = nhalf * 8 + nt;
            const bf16x8 bh = *(const bf16x8*)(B4h + (ch * 16 + ntg) * 512 + lane * 8);
            const bf16x8 bl = *(const bf16x8*)(B4l + (ch * 16 + ntg) * 512 + lane * 8);
#pragma unroll
            for (int mt = 0; mt < 4; ++mt) {
                acc[mt][nt] = MFMA(ah[mt], bh, acc[mt][nt]);
                acc[mt][nt] = MFMA(ah[mt], bl, acc[mt][nt]);
                acc[mt][nt] = MFMA(al[mt], bh, acc[mt][nt]);
            }
        }
    }

#pragma unroll
    for (int nt = 0; nt < 8; ++nt) {
        const int o = nhalf * 128 + nt * 16 + l15;
        const float bias = b4[o];
#pragma unroll
        for (int mt = 0; mt < 4; ++mt) {
#pragma unroll
            for (int rg = 0; rg < 4; ++rg) {
                const int p = p0 + mhalf * 64 + mt * 16 + kg * 4 + rg;
                outb[((long)b << 20) + (long)p * 256 + o] = acc[mt][nt][rg] + bias;
            }
        }
    }
}

// ---------- t[b][i][b'] = sum_j r2[b][i][j] * r1[b'][j] ----------
__global__ __launch_bounds__(256) void k_t(const float* __restrict__ outb,
                                           const float* __restrict__ r1,
                                           float* __restrict__ tmat) {
    __shared__ float r2c[16][256];
    __shared__ float r1c[16][260];
    int bx = blockIdx.x; int b = bx >> 4, it = bx & 15;
    int tid = threadIdx.x;
    int il = tid >> 4, bp = tid & 15;
    float acc = 0.f;
    for (int jc = 0; jc < 4096; jc += 256) {
        __syncthreads();
#pragma unroll
        for (int k = 0; k < 4; k++) {
            int f4i = tid + k * 256;
            int row = f4i >> 6, col = f4i & 63;
            *(float4*)&r2c[row][col * 4] =
                *(const float4*)(outb + ((long)b << 20) + ((long)(it * 16 + row) << 12) + jc + col * 4);
            *(float4*)&r1c[row][col * 4] =
                *(const float4*)(r1 + ((long)row << 12) + jc + col * 4);
        }
        __syncthreads();
#pragma unroll 8
        for (int j = 0; j < 256; j += 4) {
            float4 a4  = *(const float4*)&r2c[il][j];
            float4 b4v = *(const float4*)&r1c[bp][j];
            acc += a4.x * b4v.x + a4.y * b4v.y + a4.z * b4v.z + a4.w * b4v.w;
        }
    }
    tmat[((b * 256) + it * 16 + il) * 16 + bp] = acc;
}

// ---------- m2[b][i][p] = sum_b' t[b][i][b'] * r1[b'][p]  (overwrites d_out) ----------
__global__ __launch_bounds__(256) void k_m2(const float* __restrict__ tmat,
                                            const float* __restrict__ r1,
                                            float* __restrict__ outb) {
    __shared__ float r1s[16][512];
    __shared__ float ts[256];
    int bx = blockIdx.x;
    int b = bx >> 7, it = (bx >> 3) & 15, pc = bx & 7;
    int tid = threadIdx.x;
    ts[tid] = tmat[(b * 256 + it * 16) * 16 + tid];
#pragma unroll
    for (int k = 0; k < 8; k++) {
        int f4i = tid + k * 256;
        int row = f4i >> 7, col = f4i & 127;
        *(float4*)&r1s[row][col * 4] = *(const float4*)(r1 + ((long)row << 12) + pc * 512 + col * 4);
    }
    __syncthreads();
    for (int il = 0; il < 16; il++) {
        float tv[16];
#pragma unroll
        for (int bp = 0; bp < 16; bp++) tv[bp] = ts[il * 16 + bp];
#pragma unroll
        for (int k = 0; k < 2; k++) {
            int p = k * 256 + tid;
            float s = 0.f;
#pragma unroll
            for (int bp = 0; bp < 16; bp++) s += tv[bp] * r1s[bp][p];
            outb[((long)b << 20) + ((long)(it * 16 + il) << 12) + pc * 512 + p] = s;
        }
    }
}

extern "C" void kernel_launch(void* const* d_in, const int* in_sizes, int n_in,
                              void* d_out, int out_size, void* d_ws, size_t ws_size,
                              hipStream_t stream) {
    const float* x  = (const float*)d_in[0];
    const float* w1 = (const float*)d_in[1];
    const float* b1 = (const float*)d_in[2];
    const float* w2 = (const float*)d_in[3];
    const float* b2 = (const float*)d_in[4];
    const float* w3 = (const float*)d_in[5];
    const float* b3 = (const float*)d_in[6];
    const float* w4 = (const float*)d_in[7];
    const float* b4 = (const float*)d_in[8];
    float* out = (float*)d_out;

    char* p = (char*)d_ws;
    unsigned short* c1h = (unsigned short*)p;  p += 16777216L * 2;
    unsigned short* c1l = (unsigned short*)p;  p += 16777216L * 2;
    short* Bph = (short*)p;  p += 294912L * 2;
    short* Bpl = (short*)p;  p += 294912L * 2;
    short* B4h = (short*)p;  p += 65536L * 2;
    short* B4l = (short*)p;  p += 65536L * 2;
    float* gpart = (float*)p; p += 262144L * 4;
    float* scale = (float*)p; p += 4096L * 4;
    float* ga    = (float*)p; p += 4096L * 4;
    float* n_g   = (float*)p; p += 16L * 4;
    float* r1    = (float*)p; p += 65536L * 4;
    float* tmat  = (float*)p; p += 65536L * 4;

    k_wpack <<<1152, 256, 0, stream>>>(w1, Bph, Bpl);
    k_w4pack<<<256,  256, 0, stream>>>(w4, B4h, B4l);
    k_conv1 <<<512,  256, 0, stream>>>(x, Bph, Bpl, b1, c1h, c1l, gpart);
    k_mlp   <<<16,   256, 0, stream>>>(gpart, b1, w2, b2, w3, b3, scale, ga, n_g);
    k_cos   <<<1024, 256, 0, stream>>>(c1h, c1l, scale, ga, n_g, r1);
    k_conv4 <<<512,  256, 0, stream>>>(c1h, c1l, B4h, B4l, scale, b4, out);
    k_t     <<<256,  256, 0, stream>>>(out, r1, tmat);
    k_m2    <<<2048, 256, 0, stream>>>(tmat, r1, out);
}

// Round 3
// 289.743 us; speedup vs baseline: 3.0589x; 1.1703x over previous
//
#include <hip/hip_runtime.h>

#define EPSF 1e-8f

typedef __attribute__((ext_vector_type(8))) short bf16x8;
typedef __attribute__((ext_vector_type(16))) float f32x16;

#define MFMA32(a, b, c) __builtin_amdgcn_mfma_f32_32x32x16_bf16(a, b, c, 0, 0, 0)

// split f32 into (hi bf16 | lo bf16) packed in one u32: low16 = hi-part, high16 = lo-part
__device__ __forceinline__ uint32_t splitpack(float v) {
    uint32_t u = __float_as_uint(v);
    uint32_t hb = (u + 0x7fffu + ((u >> 16) & 1u)) & 0xffff0000u;  // RNE bf16 of v (f32 bits)
    float rem = v - __uint_as_float(hb);
    uint32_t r = __float_as_uint(rem);
    uint32_t lb = (r + 0x7fffu + ((r >> 16) & 1u)) >> 16;          // RNE bf16 of remainder
    return (hb >> 16) | (lb << 16);
}
__device__ __forceinline__ float bf_lo(uint32_t u) { return __uint_as_float(u << 16); }
__device__ __forceinline__ float bf_hi(uint32_t u) { return __uint_as_float(u & 0xffff0000u); }

// async global->LDS, 16B per lane. dst is per-lane (base + lane*16) so both paths agree:
// builtin takes wave-uniform base (first lane) and writes base + lane*16.
__device__ __forceinline__ void gload_lds16(const void* src, void* dst) {
#if __has_builtin(__builtin_amdgcn_global_load_lds)
    __builtin_amdgcn_global_load_lds(
        (const __attribute__((address_space(1))) uint32_t*)src,
        (__attribute__((address_space(3))) uint32_t*)dst, 16, 0, 0);
#else
    *(uint4*)dst = *(const uint4*)src;
#endif
}

// ---------- x [16][128][64][64] f32 -> hi/lo bf16 planes, frag-friendly layout ----------
// xph/xpl index: (((b*16 + cg)*64 + h)*64 + w)*8 + j   (cg = c/8, j = c%8)
__global__ __launch_bounds__(256) void k_xpack(const float* __restrict__ x,
                                               unsigned short* __restrict__ xph,
                                               unsigned short* __restrict__ xpl) {
    const int bx = blockIdx.x;                 // 4096 = b16 * cg16 * hb16
    const int hb = bx & 15, cg = (bx >> 4) & 15, b = bx >> 8;
    const int tid = threadIdx.x;
    const int w = tid & 63, hs = tid >> 6;
    const int h = hb * 4 + hs;
    uint32_t hiw[4], low[4];
#pragma unroll
    for (int q = 0; q < 4; ++q) {
        uint32_t u0 = splitpack(x[(((b * 128 + cg * 8 + q * 2) * 64) + h) * 64 + w]);
        uint32_t u1 = splitpack(x[(((b * 128 + cg * 8 + q * 2 + 1) * 64) + h) * 64 + w]);
        hiw[q] = (u0 & 0xffffu) | (u1 << 16);
        low[q] = (u0 >> 16) | (u1 & 0xffff0000u);
    }
    const long o = ((((long)(b * 16 + cg) * 64 + h) * 64) + w) * 8;
    *(uint4*)(xph + o) = *(uint4*)hiw;
    *(uint4*)(xpl + o) = *(uint4*)low;
}

// ---------- pack w1 into 32x32x16 B-frag order: [tap9][cp8][ot8][lane64][j8] ----------
__global__ __launch_bounds__(256) void k_wpack(const float* __restrict__ w1,
                                               short* __restrict__ Bh, short* __restrict__ Bl) {
    int d = blockIdx.x * 256 + threadIdx.x;    // 294912
    int j = d & 7, lane = (d >> 3) & 63, ot = (d >> 9) & 7, cp = (d >> 12) & 7, tap = d >> 15;
    int oc = ot * 32 + (lane & 31);
    int cin = cp * 16 + (lane >> 5) * 8 + j;
    uint32_t u = splitpack(w1[oc * 1152 + cin * 9 + tap]);
    Bh[d] = (short)(u & 0xffffu);
    Bl[d] = (short)(u >> 16);
}

// ---------- pack w4*scale per batch: [b16][cp8][ks2][ot8][lane64][j8] ----------
__global__ __launch_bounds__(256) void k_w4pack(const float* __restrict__ w4,
                                                const float* __restrict__ scale,
                                                short* __restrict__ W4h, short* __restrict__ W4l) {
    int d = blockIdx.x * 256 + threadIdx.x;    // 1048576
    int j = d & 7, lane = (d >> 3) & 63, ot = (d >> 9) & 7;
    int ks = (d >> 12) & 1, cp = (d >> 13) & 7, b = d >> 16;
    int oc = ot * 32 + (lane & 31);
    int c = cp * 32 + ks * 16 + (lane >> 5) * 8 + j;
    uint32_t u = splitpack(w4[oc * 256 + c] * scale[b * 256 + c]);
    W4h[d] = (short)(u & 0xffffu);
    W4l[d] = (short)(u >> 16);
}

// ---------- conv1: 3x3 SAME, bf16x3 via 32x32x16 MFMA, 2-phase gload_lds pipeline ----------
// block: 512 thr = 8 waves (2M x 4N); 128 pixels (2 h-rows x 64 w) x 256 oc.
// LDS: 2buf x 2plane x 8units(row4 x kg2) x 66wl x 16B = 33792 B.
__global__ __launch_bounds__(512, 4) void k_conv1(
        const unsigned short* __restrict__ xph, const unsigned short* __restrict__ xpl,
        const short* __restrict__ Bh, const short* __restrict__ Bl,
        const float* __restrict__ b1,
        unsigned short* __restrict__ c1h, unsigned short* __restrict__ c1l,
        float* __restrict__ gpart) {
    __shared__ uint4 lds[2112];
    const int bx = blockIdx.x;
    const int hp = bx & 31, b = bx >> 5;
    const int h0 = hp * 2;
    const int tid = threadIdx.x;
    const int lane = tid & 63, wv = tid >> 6;
    const int mhalf = wv >> 2, nq = wv & 3;
    const int l31 = lane & 31, hbit = lane >> 5;

    f32x16 acc[2][2];
#pragma unroll
    for (int i = 0; i < 2; ++i)
#pragma unroll
        for (int j = 0; j < 2; ++j)
#pragma unroll
            for (int r = 0; r < 16; ++r) acc[i][j][r] = 0.f;

    auto stage = [&](int buf, int cp) {
#pragma unroll
        for (int i = 0; i < 2; ++i) {
            const int id = wv * 2 + i;              // 0..15
            const int plane = id >> 3;
            const int row = (id >> 1) & 3, kg = id & 1;
            const int grow = h0 - 1 + row;
            uint4* dst = &lds[(((buf * 2 + plane) * 8) + (row * 2 + kg)) * 66 + 1 + lane];
            if ((unsigned)grow < 64u) {
                const unsigned short* plsrc = plane ? xpl : xph;
                const unsigned short* src =
                    plsrc + ((((long)(b * 16 + cp * 2 + kg) * 64 + grow) * 64) + lane) * 8;
                gload_lds16(src, dst);
            } else {
                *dst = (uint4){0u, 0u, 0u, 0u};
            }
        }
    };

    stage(0, 0);
    if (tid < 64) {   // halo zeros (wl=0,65) for both buffers, both planes
        const int bpl = tid >> 4, unit = (tid >> 1) & 7, side = tid & 1;
        lds[(bpl * 8 + unit) * 66 + (side ? 65 : 0)] = (uint4){0u, 0u, 0u, 0u};
    }
    __syncthreads();

    int buf = 0;
    for (int cp = 0; cp < 8; ++cp) {
        if (cp < 7) stage(buf ^ 1, cp + 1);
#pragma unroll
        for (int kh = 0; kh < 3; ++kh) {
#pragma unroll
            for (int kw = 0; kw < 3; ++kw) {
                const int tap = kh * 3 + kw;
                const int unit = (mhalf + kh) * 2 + hbit;
                bf16x8 ah[2], al[2];
#pragma unroll
                for (int mt = 0; mt < 2; ++mt) {
                    const int wl = kw + mt * 32 + l31;
                    ah[mt] = *(const bf16x8*)&lds[((buf * 2 + 0) * 8 + unit) * 66 + wl];
                    al[mt] = *(const bf16x8*)&lds[((buf * 2 + 1) * 8 + unit) * 66 + wl];
                }
#pragma unroll
                for (int nt = 0; nt < 2; ++nt) {
                    const int fi = ((tap * 8 + cp) * 8 + nq * 2 + nt) * 512 + lane * 8;
                    const bf16x8 bh = *(const bf16x8*)(Bh + fi);
                    const bf16x8 bl = *(const bf16x8*)(Bl + fi);
#pragma unroll
                    for (int mt = 0; mt < 2; ++mt) {
                        acc[mt][nt] = MFMA32(ah[mt], bh, acc[mt][nt]);
                        acc[mt][nt] = MFMA32(ah[mt], bl, acc[mt][nt]);
                        acc[mt][nt] = MFMA32(al[mt], bh, acc[mt][nt]);
                    }
                }
            }
        }
        __syncthreads();
        buf ^= 1;
    }

    const int hrow = h0 + mhalf;
#pragma unroll
    for (int nt = 0; nt < 2; ++nt) {
        const int oc = nq * 64 + nt * 32 + l31;
        float g = 0.f;
#pragma unroll
        for (int mt = 0; mt < 2; ++mt)
#pragma unroll
            for (int r = 0; r < 16; ++r) g += acc[mt][nt][r];
        g += __shfl_xor(g, 32);
        if (hbit == 0) gpart[((b * 32 + hp) * 2 + mhalf) * 256 + oc] = g;
        const float bias = b1[oc];
#pragma unroll
        for (int mt = 0; mt < 2; ++mt) {
#pragma unroll
            for (int r = 0; r < 16; ++r) {
                const int row = (r & 3) + 8 * (r >> 2) + 4 * hbit;
                const int p = hrow * 64 + mt * 32 + row;
                const uint32_t u = splitpack(acc[mt][nt][r] + bias);
                const long idx = ((long)(b * 4096 + p)) * 256 + oc;
                c1h[idx] = (unsigned short)(u & 0xffffu);
                c1l[idx] = (unsigned short)(u >> 16);
            }
        }
    }
}

// ---------- tiny MLP chain: sum gap partials, c2, c3 -> scale, ga, n_g ----------
__global__ __launch_bounds__(256) void k_mlp(const float* __restrict__ gpart,
                                             const float* __restrict__ b1,
                                             const float* __restrict__ w2, const float* __restrict__ b2,
                                             const float* __restrict__ w3, const float* __restrict__ b3,
                                             float* __restrict__ scale, float* __restrict__ ga,
                                             float* __restrict__ n_g) {
    int b = blockIdx.x, tid = threadIdx.x;
    __shared__ float gs[256], c2s[256], red[4];
    float g = 0.f;
#pragma unroll 8
    for (int i = 0; i < 64; ++i) g += gpart[(b * 64 + i) * 256 + tid];
    gs[tid] = g * (1.f / 4096.f) + b1[tid];
    __syncthreads();
    {
        const float4* wr = (const float4*)(w2 + tid * 256);
        float a = b2[tid];
#pragma unroll 8
        for (int c4 = 0; c4 < 64; c4++) {
            float4 wv = wr[c4];
            a += wv.x * gs[c4*4] + wv.y * gs[c4*4+1] + wv.z * gs[c4*4+2] + wv.w * gs[c4*4+3];
        }
        c2s[tid] = a;
    }
    __syncthreads();
    float a3 = b3[tid];
    {
        const float4* wr = (const float4*)(w3 + tid * 256);
#pragma unroll 8
        for (int c4 = 0; c4 < 64; c4++) {
            float4 wv = wr[c4];
            a3 += wv.x * c2s[c4*4] + wv.y * c2s[c4*4+1] + wv.z * c2s[c4*4+2] + wv.w * c2s[c4*4+3];
        }
    }
    float s1 = 1.f + a3;
    float g2 = gs[tid] * s1;
    scale[b * 256 + tid] = s1;
    ga[b * 256 + tid] = g2 * s1;
    float r = g2 * g2;
    for (int off = 32; off; off >>= 1) r += __shfl_down(r, off);
    if ((tid & 63) == 0) red[tid >> 6] = r;
    __syncthreads();
    if (tid == 0) n_g[b] = fmaxf(sqrtf(red[0] + red[1] + red[2] + red[3]), EPSF);
}

// ---------- cos -> r1[b][p], NHWC reads, 32-lane reduce per pixel ----------
__global__ __launch_bounds__(256) void k_cos(
        const unsigned short* __restrict__ c1h, const unsigned short* __restrict__ c1l,
        const float* __restrict__ scale, const float* __restrict__ ga,
        const float* __restrict__ n_g, float* __restrict__ r1) {
    const int bx = blockIdx.x;
    const int pt = bx & 63, b = bx >> 6;
    const int tid = threadIdx.x;
    const int lane = tid & 63, wv = tid >> 6;
    const int half = lane >> 5, l31 = lane & 31;
    const float4 fa0 = *(const float4*)(ga + b * 256 + l31 * 8);
    const float4 fa1 = *(const float4*)(ga + b * 256 + l31 * 8 + 4);
    const float4 fs0 = *(const float4*)(scale + b * 256 + l31 * 8);
    const float4 fs1 = *(const float4*)(scale + b * 256 + l31 * 8 + 4);
    const float ga8[8] = {fa0.x, fa0.y, fa0.z, fa0.w, fa1.x, fa1.y, fa1.z, fa1.w};
    const float sc8[8] = {fs0.x, fs0.y, fs0.z, fs0.w, fs1.x, fs1.y, fs1.z, fs1.w};
    const float ng = n_g[b];
#pragma unroll
    for (int pp = 0; pp < 8; ++pp) {
        const int p = pt * 64 + wv * 16 + pp * 2 + half;
        const long base = ((long)b << 20) + (long)p * 256 + l31 * 8;
        uint4 h4 = *(const uint4*)(c1h + base);
        uint4 l4 = *(const uint4*)(c1l + base);
        uint32_t hw[4] = {h4.x, h4.y, h4.z, h4.w};
        uint32_t lw[4] = {l4.x, l4.y, l4.z, l4.w};
        float num = 0.f, den = 0.f;
#pragma unroll
        for (int q = 0; q < 4; ++q) {
            float v0 = bf_lo(hw[q]) + bf_lo(lw[q]);
            float v1 = bf_hi(hw[q]) + bf_hi(lw[q]);
            num += ga8[q * 2] * v0 + ga8[q * 2 + 1] * v1;
            float t0 = sc8[q * 2] * v0, t1 = sc8[q * 2 + 1] * v1;
            den += t0 * t0 + t1 * t1;
        }
#pragma unroll
        for (int off = 1; off <= 16; off <<= 1) {
            num += __shfl_xor(num, off);
            den += __shfl_xor(den, off);
        }
        if (l31 == 0) {
            float na = fmaxf(sqrtf(den), EPSF);
            r1[b * 4096 + p] = num / (ng * na);
        }
    }
}

// ---------- conv4: 1x1, scale folded into pre-packed B; 32x32x16 MFMA; NHWC f32 out ----------
// block: 512 thr = 8 waves (2M x 4N); 128 p x 256 oc. LDS: 2buf x 2plane x 4g x 128p x 16B = 32KB.
__global__ __launch_bounds__(512, 4) void k_conv4(
        const unsigned short* __restrict__ c1h, const unsigned short* __restrict__ c1l,
        const short* __restrict__ W4h, const short* __restrict__ W4l,
        const float* __restrict__ b4, float* __restrict__ outb) {
    __shared__ uint4 lds[2048];
    const int bx = blockIdx.x;
    const int pt = bx & 31, b = bx >> 5;
    const int p0 = pt * 128;
    const int tid = threadIdx.x;
    const int lane = tid & 63, wv = tid >> 6;
    const int mhalf = wv >> 2, nq = wv & 3;
    const int l31 = lane & 31, hbit = lane >> 5;

    f32x16 acc[2][2];
#pragma unroll
    for (int i = 0; i < 2; ++i)
#pragma unroll
        for (int j = 0; j < 2; ++j)
#pragma unroll
            for (int r = 0; r < 16; ++r) acc[i][j][r] = 0.f;

    auto stage = [&](int buf, int cp) {
#pragma unroll
        for (int i = 0; i < 2; ++i) {
            const int id = wv * 2 + i;              // 0..15
            const int plane = id >> 3, g = (id >> 1) & 3, ph = id & 1;
            const unsigned short* plsrc = plane ? c1l : c1h;
            const unsigned short* src =
                plsrc + ((long)(b * 4096 + p0 + ph * 64 + lane)) * 256 + cp * 32 + g * 8;
            uint4* dst = &lds[((buf * 2 + plane) * 4 + g) * 128 + ph * 64 + lane];
            gload_lds16(src, dst);
        }
    };

    stage(0, 0);
    __syncthreads();

    int buf = 0;
    for (int cp = 0; cp < 8; ++cp) {
        if (cp < 7) stage(buf ^ 1, cp + 1);
#pragma unroll
        for (int ks = 0; ks < 2; ++ks) {
            const int g = ks * 2 + hbit;
            bf16x8 ah[2], al[2];
#pragma unroll
            for (int mt = 0; mt < 2; ++mt) {
                const int pidx = mhalf * 64 + mt * 32 + l31;
                ah[mt] = *(const bf16x8*)&lds[((buf * 2 + 0) * 4 + g) * 128 + pidx];
                al[mt] = *(const bf16x8*)&lds[((buf * 2 + 1) * 4 + g) * 128 + pidx];
            }
#pragma unroll
            for (int nt = 0; nt < 2; ++nt) {
                const int fi = ((((b * 8 + cp) * 2 + ks) * 8) + nq * 2 + nt) * 512 + lane * 8;
                const bf16x8 bh = *(const bf16x8*)(W4h + fi);
                const bf16x8 bl = *(const bf16x8*)(W4l + fi);
#pragma unroll
                for (int mt = 0; mt < 2; ++mt) {
                    acc[mt][nt] = MFMA32(ah[mt], bh, acc[mt][nt]);
                    acc[mt][nt] = MFMA32(ah[mt], bl, acc[mt][nt]);
                    acc[mt][nt] = MFMA32(al[mt], bh, acc[mt][nt]);
                }
            }
        }
        __syncthreads();
        buf ^= 1;
    }

#pragma unroll
    for (int nt = 0; nt < 2; ++nt) {
        const int o = nq * 64 + nt * 32 + l31;
        const float bias = b4[o];
#pragma unroll
        for (int mt = 0; mt < 2; ++mt) {
#pragma unroll
            for (int r = 0; r < 16; ++r) {
                const int row = (r & 3) + 8 * (r >> 2) + 4 * hbit;
                const int p = p0 + mhalf * 64 + mt * 32 + row;
                outb[((long)(b * 4096 + p)) * 256 + o] = acc[mt][nt][r] + bias;
            }
        }
    }
}

// ---------- t[b][i][b'] = sum_j r2[b][i][j] * r1[b'][j] ----------
__global__ __launch_bounds__(256) void k_t(const float* __restrict__ outb,
                                           const float* __restrict__ r1,
                                           float* __restrict__ tmat) {
    __shared__ float r2c[16][256];
    __shared__ float r1c[16][260];
    int bx = blockIdx.x; int b = bx >> 4, it = bx & 15;
    int tid = threadIdx.x;
    int il = tid >> 4, bp = tid & 15;
    float acc = 0.f;
    for (int jc = 0; jc < 4096; jc += 256) {
        __syncthreads();
#pragma unroll
        for (int k = 0; k < 4; k++) {
            int f4i = tid + k * 256;
            int row = f4i >> 6, col = f4i & 63;
            *(float4*)&r2c[row][col * 4] =
                *(const float4*)(outb + ((long)b << 20) + ((long)(it * 16 + row) << 12) + jc + col * 4);
            *(float4*)&r1c[row][col * 4] =
                *(const float4*)(r1 + ((long)row << 12) + jc + col * 4);
        }
        __syncthreads();
#pragma unroll 8
        for (int j = 0; j < 256; j += 4) {
            float4 a4  = *(const float4*)&r2c[il][j];
            float4 b4v = *(const float4*)&r1c[bp][j];
            acc += a4.x * b4v.x + a4.y * b4v.y + a4.z * b4v.z + a4.w * b4v.w;
        }
    }
    tmat[((b * 256) + it * 16 + il) * 16 + bp] = acc;
}

// ---------- m2[b][i][p] = sum_b' t[b][i][b'] * r1[b'][p]  (overwrites d_out) ----------
__global__ __launch_bounds__(256) void k_m2(const float* __restrict__ tmat,
                                            const float* __restrict__ r1,
                                            float* __restrict__ outb) {
    __shared__ float r1s[16][512];
    __shared__ float ts[256];
    int bx = blockIdx.x;
    int b = bx >> 7, it = (bx >> 3) & 15, pc = bx & 7;
    int tid = threadIdx.x;
    ts[tid] = tmat[(b * 256 + it * 16) * 16 + tid];
#pragma unroll
    for (int k = 0; k < 8; k++) {
        int f4i = tid + k * 256;
        int row = f4i >> 7, col = f4i & 127;
        *(float4*)&r1s[row][col * 4] = *(const float4*)(r1 + ((long)row << 12) + pc * 512 + col * 4);
    }
    __syncthreads();
    for (int il = 0; il < 16; il++) {
        float tv[16];
#pragma unroll
        for (int bp = 0; bp < 16; bp++) tv[bp] = ts[il * 16 + bp];
#pragma unroll
        for (int k = 0; k < 2; k++) {
            int p = k * 256 + tid;
            float s = 0.f;
#pragma unroll
            for (int bp = 0; bp < 16; bp++) s += tv[bp] * r1s[bp][p];
            outb[((long)b << 20) + ((long)(it * 16 + il) << 12) + pc * 512 + p] = s;
        }
    }
}

extern "C" void kernel_launch(void* const* d_in, const int* in_sizes, int n_in,
                              void* d_out, int out_size, void* d_ws, size_t ws_size,
                              hipStream_t stream) {
    const float* x  = (const float*)d_in[0];
    const float* w1 = (const float*)d_in[1];
    const float* b1 = (const float*)d_in[2];
    const float* w2 = (const float*)d_in[3];
    const float* b2 = (const float*)d_in[4];
    const float* w3 = (const float*)d_in[5];
    const float* b3 = (const float*)d_in[6];
    const float* w4 = (const float*)d_in[7];
    const float* b4 = (const float*)d_in[8];
    float* out = (float*)d_out;

    // xp planes live in d_out's first 32MB (dead before conv4 overwrites d_out)
    unsigned short* xph = (unsigned short*)d_out;          // 16 MB
    unsigned short* xpl = xph + 8388608L;                  // 16 MB

    char* p = (char*)d_ws;
    unsigned short* c1h = (unsigned short*)p;  p += 16777216L * 2;   // 32 MB
    unsigned short* c1l = (unsigned short*)p;  p += 16777216L * 2;   // 32 MB
    short* Bh  = (short*)p;  p += 294912L * 2;
    short* Bl  = (short*)p;  p += 294912L * 2;
    short* W4h = (short*)p;  p += 1048576L * 2;
    short* W4l = (short*)p;  p += 1048576L * 2;
    float* gpart = (float*)p; p += 262144L * 4;
    float* scale = (float*)p; p += 4096L * 4;
    float* ga    = (float*)p; p += 4096L * 4;
    float* n_g   = (float*)p; p += 16L * 4;
    float* r1    = (float*)p; p += 65536L * 4;
    float* tmat  = (float*)p; p += 65536L * 4;

    k_xpack <<<4096, 256, 0, stream>>>(x, xph, xpl);
    k_wpack <<<1152, 256, 0, stream>>>(w1, Bh, Bl);
    k_conv1 <<<512,  512, 0, stream>>>(xph, xpl, Bh, Bl, b1, c1h, c1l, gpart);
    k_mlp   <<<16,   256, 0, stream>>>(gpart, b1, w2, b2, w3, b3, scale, ga, n_g);
    k_w4pack<<<4096, 256, 0, stream>>>(w4, scale, W4h, W4l);
    k_cos   <<<1024, 256, 0, stream>>>(c1h, c1l, scale, ga, n_g, r1);
    k_conv4 <<<512,  512, 0, stream>>>(c1h, c1l, W4h, W4l, b4, out);
    k_t     <<<256,  256, 0, stream>>>(out, r1, tmat);
    k_m2    <<<2048, 256, 0, stream>>>(tmat, r1, out);
}

// Round 4
// 251.151 us; speedup vs baseline: 3.5289x; 1.1537x over previous
//
#include <hip/hip_runtime.h>

#define EPSF 1e-8f

typedef __attribute__((ext_vector_type(8))) short bf16x8;
typedef __attribute__((ext_vector_type(16))) float f32x16;

#define MFMA32(a, b, c) __builtin_amdgcn_mfma_f32_32x32x16_bf16(a, b, c, 0, 0, 0)

// split f32 into (hi bf16 | lo bf16) packed in one u32: low16 = hi-part, high16 = lo-part
__device__ __forceinline__ uint32_t splitpack(float v) {
    uint32_t u = __float_as_uint(v);
    uint32_t hb = (u + 0x7fffu + ((u >> 16) & 1u)) & 0xffff0000u;  // RNE bf16 of v (f32 bits)
    float rem = v - __uint_as_float(hb);
    uint32_t r = __float_as_uint(rem);
    uint32_t lb = (r + 0x7fffu + ((r >> 16) & 1u)) >> 16;          // RNE bf16 of remainder
    return (hb >> 16) | (lb << 16);
}
__device__ __forceinline__ float unpackf(uint32_t p) {
    return __uint_as_float(p << 16) + __uint_as_float(p & 0xffff0000u);
}

// 8 packed u32 (= 8 channels) -> hi/lo bf16x8 fragments
__device__ __forceinline__ void unpack_frag(uint4 a, uint4 b, bf16x8& hi, bf16x8& lo) {
    union { uint32_t w[4]; bf16x8 v; } H, L;
    H.w[0] = (a.x & 0xffffu) | (a.y << 16);
    H.w[1] = (a.z & 0xffffu) | (a.w << 16);
    H.w[2] = (b.x & 0xffffu) | (b.y << 16);
    H.w[3] = (b.z & 0xffffu) | (b.w << 16);
    L.w[0] = (a.x >> 16) | (a.y & 0xffff0000u);
    L.w[1] = (a.z >> 16) | (a.w & 0xffff0000u);
    L.w[2] = (b.x >> 16) | (b.y & 0xffff0000u);
    L.w[3] = (b.z >> 16) | (b.w & 0xffff0000u);
    hi = H.v; lo = L.v;
}

// async global->LDS, 16B per lane; dst passed per-lane (base + lane*16) consistent with HW.
__device__ __forceinline__ void gload_lds16(const void* src, void* dst) {
#if __has_builtin(__builtin_amdgcn_global_load_lds)
    __builtin_amdgcn_global_load_lds(
        (const __attribute__((address_space(1))) uint32_t*)src,
        (__attribute__((address_space(3))) uint32_t*)dst, 16, 0, 0);
#else
    *(uint4*)dst = *(const uint4*)src;
#endif
}

// ---------- x [16][128][64][64] f32 -> hi/lo bf16 planes, frag-friendly layout ----------
// xph/xpl index: (((b*16 + cg)*64 + h)*64 + w)*8 + j   (cg = c/8, j = c%8)
__global__ __launch_bounds__(256) void k_xpack(const float* __restrict__ x,
                                               unsigned short* __restrict__ xph,
                                               unsigned short* __restrict__ xpl) {
    const int bx = blockIdx.x;                 // 4096 = b16 * cg16 * hb16
    const int hb = bx & 15, cg = (bx >> 4) & 15, b = bx >> 8;
    const int tid = threadIdx.x;
    const int w = tid & 63, hs = tid >> 6;
    const int h = hb * 4 + hs;
    uint32_t hiw[4], low[4];
#pragma unroll
    for (int q = 0; q < 4; ++q) {
        uint32_t u0 = splitpack(x[(((b * 128 + cg * 8 + q * 2) * 64) + h) * 64 + w]);
        uint32_t u1 = splitpack(x[(((b * 128 + cg * 8 + q * 2 + 1) * 64) + h) * 64 + w]);
        hiw[q] = (u0 & 0xffffu) | (u1 << 16);
        low[q] = (u0 >> 16) | (u1 & 0xffff0000u);
    }
    const long o = ((((long)(b * 16 + cg) * 64 + h) * 64) + w) * 8;
    *(uint4*)(xph + o) = *(uint4*)hiw;
    *(uint4*)(xpl + o) = *(uint4*)low;
}

// ---------- pack w1 into 32x32x16 B-frag order: [tap9][cp8][ot8][lane64][j8] ----------
__global__ __launch_bounds__(256) void k_wpack(const float* __restrict__ w1,
                                               short* __restrict__ Bh, short* __restrict__ Bl) {
    int d = blockIdx.x * 256 + threadIdx.x;    // 294912
    int j = d & 7, lane = (d >> 3) & 63, ot = (d >> 9) & 7, cp = (d >> 12) & 7, tap = d >> 15;
    int oc = ot * 32 + (lane & 31);
    int cin = cp * 16 + (lane >> 5) * 8 + j;
    uint32_t u = splitpack(w1[oc * 1152 + cin * 9 + tap]);
    Bh[d] = (short)(u & 0xffffu);
    Bl[d] = (short)(u >> 16);
}

// ---------- pack w4*scale per batch: [b16][cp8][ks2][ot8][lane64][j8] ----------
__global__ __launch_bounds__(256) void k_w4pack(const float* __restrict__ w4,
                                                const float* __restrict__ scale,
                                                short* __restrict__ W4h, short* __restrict__ W4l) {
    int d = blockIdx.x * 256 + threadIdx.x;    // 1048576
    int j = d & 7, lane = (d >> 3) & 63, ot = (d >> 9) & 7;
    int ks = (d >> 12) & 1, cp = (d >> 13) & 7, b = d >> 16;
    int oc = ot * 32 + (lane & 31);
    int c = cp * 32 + ks * 16 + (lane >> 5) * 8 + j;
    uint32_t u = splitpack(w4[oc * 256 + c] * scale[b * 256 + c]);
    W4h[d] = (short)(u & 0xffffu);
    W4l[d] = (short)(u >> 16);
}

// ---------- conv1: 3x3 SAME, bf16x3 via 32x32x16 MFMA, tap-pipelined frag prefetch ----------
// block: 512 thr = 8 waves (4M x 2N); 256 pixels (4 h-rows x 64 w) x 128 oc.
// LDS: 2buf x 2plane x 12units(row6 x kg2) x 66wl x 16B = 50688 B.
__global__ __launch_bounds__(512, 2) void k_conv1(
        const unsigned short* __restrict__ xph, const unsigned short* __restrict__ xpl,
        const short* __restrict__ Bh, const short* __restrict__ Bl,
        const float* __restrict__ b1,
        uint32_t* __restrict__ c1p, float* __restrict__ gpart) {
    __shared__ uint4 lds[2 * 2 * 12 * 66];
    const int bx = blockIdx.x;                 // 512 = b16 * hp16 * oh2
    const int oh = bx & 1, hp = (bx >> 1) & 15, b = bx >> 5;
    const int h0 = hp * 4;
    const int tid = threadIdx.x;
    const int lane = tid & 63, wv = tid >> 6;
    const int mq = wv >> 1, nh = wv & 1;
    const int l31 = lane & 31, hbit = lane >> 5;

    f32x16 acc[2][2];
#pragma unroll
    for (int i = 0; i < 2; ++i)
#pragma unroll
        for (int j = 0; j < 2; ++j)
#pragma unroll
            for (int r = 0; r < 16; ++r) acc[i][j][r] = 0.f;

    auto stage = [&](int buf, int cp) {
#pragma unroll
        for (int i = 0; i < 3; ++i) {
            const int id = wv * 3 + i;              // 0..23
            const int plane = (id >= 12) ? 1 : 0;
            const int u = id - plane * 12;          // 0..11
            const int r6 = u >> 1, kg = u & 1;
            const int grow = h0 - 1 + r6;
            uint4* dst = &lds[((buf * 2 + plane) * 12 + u) * 66 + 1 + lane];
            if ((unsigned)grow < 64u) {
                const unsigned short* pls = plane ? xpl : xph;
                const unsigned short* src =
                    pls + ((((long)(b * 16 + cp * 2 + kg) * 64 + grow) * 64) + lane) * 8;
                gload_lds16(src, dst);
            } else {
                *dst = (uint4){0u, 0u, 0u, 0u};
            }
        }
    };

    stage(0, 0);
    if (tid < 96) {   // halo zeros (wl = 0, 65) for all buf/plane/units
        const int row = tid >> 1, side = tid & 1;
        lds[row * 66 + (side ? 65 : 0)] = (uint4){0u, 0u, 0u, 0u};
    }
    __syncthreads();

    int buf = 0;
    for (int cp = 0; cp < 8; ++cp) {
        if (cp < 7) stage(buf ^ 1, cp + 1);
        bf16x8 Ah[2][2], Al[2][2], Bhv[2][2], Blv[2][2];
#define LOADA(tap, par) do {                                                     \
            const int kh_ = (tap) / 3, kw_ = (tap) % 3;                          \
            _Pragma("unroll")                                                    \
            for (int mt = 0; mt < 2; ++mt) {                                     \
                const int rb = ((buf * 2 + 0) * 12 + (mq + kh_) * 2 + hbit) * 66 \
                               + kw_ + mt * 32 + l31;                            \
                const int rb1 = rb + 12 * 66;                                    \
                Ah[par][mt] = *(const bf16x8*)&lds[rb];                          \
                Al[par][mt] = *(const bf16x8*)&lds[rb1];                         \
            } } while (0)
#define LOADB(tap, par) do {                                                     \
            _Pragma("unroll")                                                    \
            for (int nt = 0; nt < 2; ++nt) {                                     \
                const int fi = (((tap) * 8 + cp) * 8 + oh * 4 + nh * 2 + nt) * 512 + lane * 8; \
                Bhv[par][nt] = *(const bf16x8*)(Bh + fi);                        \
                Blv[par][nt] = *(const bf16x8*)(Bl + fi);                        \
            } } while (0)
        LOADA(0, 0); LOADB(0, 0);
#pragma unroll
        for (int tap = 0; tap < 9; ++tap) {
            const int cur = tap & 1, nxt = cur ^ 1;
            if (tap < 8) { LOADA(tap + 1, nxt); LOADB(tap + 1, nxt); }
#pragma unroll
            for (int nt = 0; nt < 2; ++nt)
#pragma unroll
                for (int mt = 0; mt < 2; ++mt) {
                    acc[mt][nt] = MFMA32(Ah[cur][mt], Bhv[cur][nt], acc[mt][nt]);
                    acc[mt][nt] = MFMA32(Ah[cur][mt], Blv[cur][nt], acc[mt][nt]);
                    acc[mt][nt] = MFMA32(Al[cur][mt], Bhv[cur][nt], acc[mt][nt]);
                }
        }
#undef LOADA
#undef LOADB
        __syncthreads();
        buf ^= 1;
    }

    const int hrow = h0 + mq;
#pragma unroll
    for (int nt = 0; nt < 2; ++nt) {
        const int oc = oh * 128 + nh * 64 + nt * 32 + l31;
        float g = 0.f;
#pragma unroll
        for (int mt = 0; mt < 2; ++mt)
#pragma unroll
            for (int r = 0; r < 16; ++r) g += acc[mt][nt][r];
        g += __shfl_xor(g, 32);
        if (hbit == 0) gpart[((b * 16 + hp) * 4 + mq) * 256 + oc] = g;
        const float bias = b1[oc];
#pragma unroll
        for (int mt = 0; mt < 2; ++mt) {
#pragma unroll
            for (int r = 0; r < 16; ++r) {
                const int row = (r & 3) + 8 * (r >> 2) + 4 * hbit;
                const int p = hrow * 64 + mt * 32 + row;
                c1p[((long)(b * 4096 + p)) * 256 + oc] = splitpack(acc[mt][nt][r] + bias);
            }
        }
    }
}

// ---------- tiny MLP chain: sum gap partials, c2, c3 -> scale, ga, n_g ----------
__global__ __launch_bounds__(256) void k_mlp(const float* __restrict__ gpart,
                                             const float* __restrict__ b1,
                                             const float* __restrict__ w2, const float* __restrict__ b2,
                                             const float* __restrict__ w3, const float* __restrict__ b3,
                                             float* __restrict__ scale, float* __restrict__ ga,
                                             float* __restrict__ n_g) {
    int b = blockIdx.x, tid = threadIdx.x;
    __shared__ float gs[256], c2s[256], red[4];
    float g = 0.f;
#pragma unroll 8
    for (int i = 0; i < 64; ++i) g += gpart[(b * 64 + i) * 256 + tid];
    gs[tid] = g * (1.f / 4096.f) + b1[tid];
    __syncthreads();
    {
        const float4* wr = (const float4*)(w2 + tid * 256);
        float a = b2[tid];
#pragma unroll 8
        for (int c4 = 0; c4 < 64; c4++) {
            float4 wv = wr[c4];
            a += wv.x * gs[c4*4] + wv.y * gs[c4*4+1] + wv.z * gs[c4*4+2] + wv.w * gs[c4*4+3];
        }
        c2s[tid] = a;
    }
    __syncthreads();
    float a3 = b3[tid];
    {
        const float4* wr = (const float4*)(w3 + tid * 256);
#pragma unroll 8
        for (int c4 = 0; c4 < 64; c4++) {
            float4 wv = wr[c4];
            a3 += wv.x * c2s[c4*4] + wv.y * c2s[c4*4+1] + wv.z * c2s[c4*4+2] + wv.w * c2s[c4*4+3];
        }
    }
    float s1 = 1.f + a3;
    float g2 = gs[tid] * s1;
    scale[b * 256 + tid] = s1;
    ga[b * 256 + tid] = g2 * s1;
    float r = g2 * g2;
    for (int off = 32; off; off >>= 1) r += __shfl_down(r, off);
    if ((tid & 63) == 0) red[tid >> 6] = r;
    __syncthreads();
    if (tid == 0) n_g[b] = fmaxf(sqrtf(red[0] + red[1] + red[2] + red[3]), EPSF);
}

// ---------- conv4 (+ fused cos/r1): A = packed c1, B = w4*scale prepacked; NHWC f32 out ----------
// block: 512 thr = 8 waves (2M x 4N); 128 p x 256 oc. LDS tile: [buf2][p128][q8] uint4 = 32 KB.
// Pre-swizzled staging: LDS[p][q] holds global quad q ^ (p&7); reads XOR back.
__global__ __launch_bounds__(512, 2) void k_conv4(
        const uint32_t* __restrict__ c1p,
        const short* __restrict__ W4h, const short* __restrict__ W4l,
        const float* __restrict__ b4, const float* __restrict__ scale,
        const float* __restrict__ ga, const float* __restrict__ n_g,
        float* __restrict__ outb, float* __restrict__ r1) {
    __shared__ uint4 lds4[2 * 128 * 8];
    __shared__ float scs[256], gas[256];
    __shared__ float cred[128 * 8];
    const int bx = blockIdx.x;                 // 512 = b16 * pt32
    const int pt = bx & 31, b = bx >> 5;
    const int p0 = pt * 128;
    const int tid = threadIdx.x;
    const int lane = tid & 63, wv = tid >> 6;
    const int mhalf = wv >> 2, nq = wv & 3;
    const int l31 = lane & 31, hbit = lane >> 5;
    const int pc = tid & 127, cq = tid >> 7;   // cos roles
    const float ng = n_g[b];

    if (tid < 256) { scs[tid] = scale[b * 256 + tid]; gas[tid] = ga[b * 256 + tid]; }

    f32x16 acc[2][2];
#pragma unroll
    for (int i = 0; i < 2; ++i)
#pragma unroll
        for (int j = 0; j < 2; ++j)
#pragma unroll
            for (int r = 0; r < 16; ++r) acc[i][j][r] = 0.f;

    const int qsrc = (lane & 7) ^ (lane >> 3);
    auto stage = [&](int buf, int cp) {
#pragma unroll
        for (int i = 0; i < 2; ++i) {
            const int id = wv * 2 + i;              // 0..15
            const int pbase = id * 8;
            const uint32_t* src = c1p + ((long)(b * 4096 + p0 + pbase + (lane >> 3))) * 256
                                  + cp * 32 + qsrc * 4;
            uint4* dst = &lds4[buf * 1024 + pbase * 8 + lane];
            gload_lds16(src, dst);
        }
    };

    stage(0, 0);
    __syncthreads();

    float cnum = 0.f, cden = 0.f;
    int buf = 0;
    for (int cp = 0; cp < 8; ++cp) {
        if (cp < 7) stage(buf ^ 1, cp + 1);
        {   // fused cos accumulation from the staged tile
            uint4 a = lds4[buf * 1024 + pc * 8 + ((cq * 2) ^ (pc & 7))];
            uint4 bq = lds4[buf * 1024 + pc * 8 + ((cq * 2 + 1) ^ (pc & 7))];
            uint32_t pk[8] = {a.x, a.y, a.z, a.w, bq.x, bq.y, bq.z, bq.w};
#pragma unroll
            for (int j = 0; j < 8; ++j) {
                const float v = unpackf(pk[j]);
                const int c = cp * 32 + cq * 8 + j;
                cnum += gas[c] * v;
                const float t = scs[c] * v;
                cden += t * t;
            }
        }
        bf16x8 Wh[2][2], Wl[2][2];
#define LOADW(cp_, ks_, par) do {                                                \
            _Pragma("unroll")                                                    \
            for (int nt = 0; nt < 2; ++nt) {                                     \
                const int fi = ((((b * 8 + (cp_)) * 2 + (ks_)) * 8) + nq * 2 + nt) * 512 + lane * 8; \
                Wh[par][nt] = *(const bf16x8*)(W4h + fi);                        \
                Wl[par][nt] = *(const bf16x8*)(W4l + fi);                        \
            } } while (0)
        LOADW(cp, 0, 0);
#pragma unroll
        for (int ks = 0; ks < 2; ++ks) {
            if (ks == 0) LOADW(cp, 1, 1);
            bf16x8 ah[2], al[2];
#pragma unroll
            for (int mt = 0; mt < 2; ++mt) {
                const int pidx = mhalf * 64 + mt * 32 + l31;
                const int g = ks * 2 + hbit;
                uint4 ua = lds4[buf * 1024 + pidx * 8 + ((g * 2) ^ (pidx & 7))];
                uint4 ub = lds4[buf * 1024 + pidx * 8 + ((g * 2 + 1) ^ (pidx & 7))];
                unpack_frag(ua, ub, ah[mt], al[mt]);
            }
#pragma unroll
            for (int nt = 0; nt < 2; ++nt)
#pragma unroll
                for (int mt = 0; mt < 2; ++mt) {
                    acc[mt][nt] = MFMA32(ah[mt], Wh[ks][nt], acc[mt][nt]);
                    acc[mt][nt] = MFMA32(ah[mt], Wl[ks][nt], acc[mt][nt]);
                    acc[mt][nt] = MFMA32(al[mt], Wh[ks][nt], acc[mt][nt]);
                }
        }
#undef LOADW
        __syncthreads();
        buf ^= 1;
    }

    // cos reduce + r1
    cred[pc * 8 + cq] = cnum;
    cred[pc * 8 + 4 + cq] = cden;
    __syncthreads();
    if (tid < 128) {
        const float n = cred[tid * 8] + cred[tid * 8 + 1] + cred[tid * 8 + 2] + cred[tid * 8 + 3];
        const float d = cred[tid * 8 + 4] + cred[tid * 8 + 5] + cred[tid * 8 + 6] + cred[tid * 8 + 7];
        r1[b * 4096 + p0 + tid] = n / (fmaxf(sqrtf(d), EPSF) * ng);
    }

#pragma unroll
    for (int nt = 0; nt < 2; ++nt) {
        const int o = nq * 64 + nt * 32 + l31;
        const float bias = b4[o];
#pragma unroll
        for (int mt = 0; mt < 2; ++mt) {
#pragma unroll
            for (int r = 0; r < 16; ++r) {
                const int row = (r & 3) + 8 * (r >> 2) + 4 * hbit;
                const int p = p0 + mhalf * 64 + mt * 32 + row;
                outb[((long)(b * 4096 + p)) * 256 + o] = acc[mt][nt][r] + bias;
            }
        }
    }
}

// ---------- t[b][i][b'] = sum_j r2[b][i][j] * r1[b'][j] ----------
__global__ __launch_bounds__(256) void k_t(const float* __restrict__ outb,
                                           const float* __restrict__ r1,
                                           float* __restrict__ tmat) {
    __shared__ float r2c[16][256];
    __shared__ float r1c[16][260];
    int bx = blockIdx.x; int b = bx >> 4, it = bx & 15;
    int tid = threadIdx.x;
    int il = tid >> 4, bp = tid & 15;
    float acc = 0.f;
    for (int jc = 0; jc < 4096; jc += 256) {
        __syncthreads();
#pragma unroll
        for (int k = 0; k < 4; k++) {
            int f4i = tid + k * 256;
            int row = f4i >> 6, col = f4i & 63;
            *(float4*)&r2c[row][col * 4] =
                *(const float4*)(outb + ((long)b << 20) + ((long)(it * 16 + row) << 12) + jc + col * 4);
            *(float4*)&r1c[row][col * 4] =
                *(const float4*)(r1 + ((long)row << 12) + jc + col * 4);
        }
        __syncthreads();
#pragma unroll 8
        for (int j = 0; j < 256; j += 4) {
            float4 a4  = *(const float4*)&r2c[il][j];
            float4 b4v = *(const float4*)&r1c[bp][j];
            acc += a4.x * b4v.x + a4.y * b4v.y + a4.z * b4v.z + a4.w * b4v.w;
        }
    }
    tmat[((b * 256) + it * 16 + il) * 16 + bp] = acc;
}

// ---------- m2[b][i][p] = sum_b' t[b][i][b'] * r1[b'][p]  (overwrites d_out) ----------
__global__ __launch_bounds__(256) void k_m2(const float* __restrict__ tmat,
                                            const float* __restrict__ r1,
                                            float* __restrict__ outb) {
    __shared__ float r1s[16][512];
    __shared__ float ts[256];
    int bx = blockIdx.x;
    int b = bx >> 7, it = (bx >> 3) & 15, pc = bx & 7;
    int tid = threadIdx.x;
    ts[tid] = tmat[(b * 256 + it * 16) * 16 + tid];
#pragma unroll
    for (int k = 0; k < 8; k++) {
        int f4i = tid + k * 256;
        int row = f4i >> 7, col = f4i & 127;
        *(float4*)&r1s[row][col * 4] = *(const float4*)(r1 + ((long)row << 12) + pc * 512 + col * 4);
    }
    __syncthreads();
    for (int il = 0; il < 16; il++) {
        float tv[16];
#pragma unroll
        for (int bp = 0; bp < 16; bp++) tv[bp] = ts[il * 16 + bp];
#pragma unroll
        for (int k = 0; k < 2; k++) {
            int p = k * 256 + tid;
            float s = 0.f;
#pragma unroll
            for (int bp = 0; bp < 16; bp++) s += tv[bp] * r1s[bp][p];
            outb[((long)b << 20) + ((long)(it * 16 + il) << 12) + pc * 512 + p] = s;
        }
    }
}

extern "C" void kernel_launch(void* const* d_in, const int* in_sizes, int n_in,
                              void* d_out, int out_size, void* d_ws, size_t ws_size,
                              hipStream_t stream) {
    const float* x  = (const float*)d_in[0];
    const float* w1 = (const float*)d_in[1];
    const float* b1 = (const float*)d_in[2];
    const float* w2 = (const float*)d_in[3];
    const float* b2 = (const float*)d_in[4];
    const float* w3 = (const float*)d_in[5];
    const float* b3 = (const float*)d_in[6];
    const float* w4 = (const float*)d_in[7];
    const float* b4 = (const float*)d_in[8];
    float* out = (float*)d_out;

    // xp planes live in d_out's first 32MB (dead before conv4 overwrites d_out)
    unsigned short* xph = (unsigned short*)d_out;          // 16 MB
    unsigned short* xpl = xph + 8388608L;                  // 16 MB

    char* p = (char*)d_ws;
    uint32_t* c1p = (uint32_t*)p;  p += 16777216L * 4;     // 64 MB packed hi|lo
    short* Bh  = (short*)p;  p += 294912L * 2;
    short* Bl  = (short*)p;  p += 294912L * 2;
    short* W4h = (short*)p;  p += 1048576L * 2;
    short* W4l = (short*)p;  p += 1048576L * 2;
    float* gpart = (float*)p; p += 262144L * 4;
    float* scale = (float*)p; p += 4096L * 4;
    float* ga    = (float*)p; p += 4096L * 4;
    float* n_g   = (float*)p; p += 16L * 4;
    float* r1    = (float*)p; p += 65536L * 4;
    float* tmat  = (float*)p; p += 65536L * 4;

    k_xpack <<<4096, 256, 0, stream>>>(x, xph, xpl);
    k_wpack <<<1152, 256, 0, stream>>>(w1, Bh, Bl);
    k_conv1 <<<512,  512, 0, stream>>>(xph, xpl, Bh, Bl, b1, c1p, gpart);
    k_mlp   <<<16,   256, 0, stream>>>(gpart, b1, w2, b2, w3, b3, scale, ga, n_g);
    k_w4pack<<<4096, 256, 0, stream>>>(w4, scale, W4h, W4l);
    k_conv4 <<<512,  512, 0, stream>>>(c1p, W4h, W4l, b4, scale, ga, n_g, out, r1);
    k_t     <<<256,  256, 0, stream>>>(out, r1, tmat);
    k_m2    <<<2048, 256, 0, stream>>>(tmat, r1, out);
}

// Round 5
// 243.733 us; speedup vs baseline: 3.6364x; 1.0304x over previous
//
#include <hip/hip_runtime.h>

#define EPSF 1e-8f

typedef __attribute__((ext_vector_type(8))) short bf16x8;
typedef __attribute__((ext_vector_type(16))) float f32x16;

#define MFMA32(a, b, c) __builtin_amdgcn_mfma_f32_32x32x16_bf16(a, b, c, 0, 0, 0)

// split f32 into (hi bf16 | lo bf16) packed in one u32: low16 = hi-part, high16 = lo-part
__device__ __forceinline__ uint32_t splitpack(float v) {
    uint32_t u = __float_as_uint(v);
    uint32_t hb = (u + 0x7fffu + ((u >> 16) & 1u)) & 0xffff0000u;  // RNE bf16 of v (f32 bits)
    float rem = v - __uint_as_float(hb);
    uint32_t r = __float_as_uint(rem);
    uint32_t lb = (r + 0x7fffu + ((r >> 16) & 1u)) >> 16;          // RNE bf16 of remainder
    return (hb >> 16) | (lb << 16);
}
__device__ __forceinline__ float unpackf(uint32_t p) {
    return __uint_as_float(p << 16) + __uint_as_float(p & 0xffff0000u);
}

// async global->LDS, 16B per lane; dst passed per-lane (base + lane*16) consistent with HW.
__device__ __forceinline__ void gload_lds16(const void* src, void* dst) {
#if __has_builtin(__builtin_amdgcn_global_load_lds)
    __builtin_amdgcn_global_load_lds(
        (const __attribute__((address_space(1))) uint32_t*)src,
        (__attribute__((address_space(3))) uint32_t*)dst, 16, 0, 0);
#else
    *(uint4*)dst = *(const uint4*)src;
#endif
}

// ---------- x [16][128][64][64] f32 -> hi/lo bf16 planes, frag-friendly layout ----------
__global__ __launch_bounds__(256) void k_xpack(const float* __restrict__ x,
                                               unsigned short* __restrict__ xph,
                                               unsigned short* __restrict__ xpl) {
    const int bx = blockIdx.x;                 // 4096 = b16 * cg16 * hb16
    const int hb = bx & 15, cg = (bx >> 4) & 15, b = bx >> 8;
    const int tid = threadIdx.x;
    const int w = tid & 63, hs = tid >> 6;
    const int h = hb * 4 + hs;
    uint32_t hiw[4], low[4];
#pragma unroll
    for (int q = 0; q < 4; ++q) {
        uint32_t u0 = splitpack(x[(((b * 128 + cg * 8 + q * 2) * 64) + h) * 64 + w]);
        uint32_t u1 = splitpack(x[(((b * 128 + cg * 8 + q * 2 + 1) * 64) + h) * 64 + w]);
        hiw[q] = (u0 & 0xffffu) | (u1 << 16);
        low[q] = (u0 >> 16) | (u1 & 0xffff0000u);
    }
    const long o = ((((long)(b * 16 + cg) * 64 + h) * 64) + w) * 8;
    *(uint4*)(xph + o) = *(uint4*)hiw;
    *(uint4*)(xpl + o) = *(uint4*)low;
}

// ---------- pack w1 into 32x32x16 B-frag order: [tap9][cp8][ntile8][lane64][j8] ----------
__global__ __launch_bounds__(256) void k_wpack(const float* __restrict__ w1,
                                               short* __restrict__ Bh, short* __restrict__ Bl) {
    int d = blockIdx.x * 256 + threadIdx.x;    // 294912
    int j = d & 7, lane = (d >> 3) & 63, nt = (d >> 9) & 7, cp = (d >> 12) & 7, tap = d >> 15;
    int oc = nt * 32 + (lane & 31);
    int cin = cp * 16 + (lane >> 5) * 8 + j;
    uint32_t u = splitpack(w1[oc * 1152 + cin * 9 + tap]);
    Bh[d] = (short)(u & 0xffffu);
    Bl[d] = (short)(u >> 16);
}

// ---------- conv1: 3x3 SAME, bf16x3 via 32x32x16 MFMA, tap-pipelined frag prefetch ----------
// block: 512 thr = 8 waves (4M x 2N); 256 pixels (4 h-rows x 64 w) x 64 oc.
// wave = 64p x 32oc -> acc[2] (32 regs), targets <=128 combined regs = 16 waves/CU.
// LDS: 2buf x 2plane x 12units(row6 x kg2) x 66wl x 16B = 50688 B.
__global__ __launch_bounds__(512, 4) void k_conv1(
        const unsigned short* __restrict__ xph, const unsigned short* __restrict__ xpl,
        const short* __restrict__ Bh, const short* __restrict__ Bl,
        const float* __restrict__ b1,
        uint32_t* __restrict__ c1p, float* __restrict__ gpart) {
    __shared__ uint4 lds[2 * 2 * 12 * 66];
    const int bx = blockIdx.x;                 // 1024 = b16 * hp16 * ot4
    const int ot = bx & 3, hp = (bx >> 2) & 15, b = bx >> 6;
    const int h0 = hp * 4;
    const int tid = threadIdx.x;
    const int lane = tid & 63, wv = tid >> 6;
    const int mq = wv >> 1, nh = wv & 1;
    const int l31 = lane & 31, hbit = lane >> 5;

    f32x16 acc[2];
#pragma unroll
    for (int i = 0; i < 2; ++i)
#pragma unroll
        for (int r = 0; r < 16; ++r) acc[i][r] = 0.f;

    auto stage = [&](int buf, int cp) {
#pragma unroll
        for (int i = 0; i < 3; ++i) {
            const int id = wv * 3 + i;              // 0..23
            const int plane = (id >= 12) ? 1 : 0;
            const int u = id - plane * 12;          // 0..11
            const int r6 = u >> 1, kg = u & 1;
            const int grow = h0 - 1 + r6;
            uint4* dst = &lds[((buf * 2 + plane) * 12 + u) * 66 + 1 + lane];
            if ((unsigned)grow < 64u) {
                const unsigned short* pls = plane ? xpl : xph;
                const unsigned short* src =
                    pls + ((((long)(b * 16 + cp * 2 + kg) * 64 + grow) * 64) + lane) * 8;
                gload_lds16(src, dst);
            } else {
                *dst = (uint4){0u, 0u, 0u, 0u};
            }
        }
    };

    stage(0, 0);
    if (tid < 96) {   // halo zeros (wl = 0, 65) for all buf/plane/units
        const int row = tid >> 1, side = tid & 1;
        lds[row * 66 + (side ? 65 : 0)] = (uint4){0u, 0u, 0u, 0u};
    }
    __syncthreads();

    int buf = 0;
    for (int cp = 0; cp < 8; ++cp) {
        if (cp < 7) stage(buf ^ 1, cp + 1);
        bf16x8 Ah[2][2], Al[2][2], Bhv[2], Blv[2];
#define LOADA(tap, par) do {                                                     \
            const int kh_ = (tap) / 3, kw_ = (tap) % 3;                          \
            _Pragma("unroll")                                                    \
            for (int mt = 0; mt < 2; ++mt) {                                     \
                const int rb = ((buf * 2 + 0) * 12 + (mq + kh_) * 2 + hbit) * 66 \
                               + kw_ + mt * 32 + l31;                            \
                const int rb1 = rb + 12 * 66;                                    \
                Ah[par][mt] = *(const bf16x8*)&lds[rb];                          \
                Al[par][mt] = *(const bf16x8*)&lds[rb1];                         \
            } } while (0)
#define LOADB(tap, par) do {                                                     \
            const int fi = (((tap) * 8 + cp) * 8 + ot * 2 + nh) * 512 + lane * 8; \
            Bhv[par] = *(const bf16x8*)(Bh + fi);                                \
            Blv[par] = *(const bf16x8*)(Bl + fi);                                \
        } while (0)
        LOADA(0, 0); LOADB(0, 0);
#pragma unroll
        for (int tap = 0; tap < 9; ++tap) {
            const int cur = tap & 1, nxt = cur ^ 1;
            if (tap < 8) { LOADA(tap + 1, nxt); LOADB(tap + 1, nxt); }
            __builtin_amdgcn_s_setprio(1);
#pragma unroll
            for (int mt = 0; mt < 2; ++mt) {
                acc[mt] = MFMA32(Ah[cur][mt], Bhv[cur], acc[mt]);
                acc[mt] = MFMA32(Ah[cur][mt], Blv[cur], acc[mt]);
                acc[mt] = MFMA32(Al[cur][mt], Bhv[cur], acc[mt]);
            }
            __builtin_amdgcn_s_setprio(0);
        }
#undef LOADA
#undef LOADB
        __syncthreads();
        buf ^= 1;
    }

    const int hrow = h0 + mq;
    const int oc = ot * 64 + nh * 32 + l31;
    {
        float g = 0.f;
#pragma unroll
        for (int mt = 0; mt < 2; ++mt)
#pragma unroll
            for (int r = 0; r < 16; ++r) g += acc[mt][r];
        g += __shfl_xor(g, 32);
        if (hbit == 0) gpart[((b * 16 + hp) * 4 + mq) * 256 + oc] = g;
    }
    const float bias = b1[oc];
#pragma unroll
    for (int mt = 0; mt < 2; ++mt) {
#pragma unroll
        for (int r = 0; r < 16; ++r) {
            const int row = (r & 3) + 8 * (r >> 2) + 4 * hbit;
            const int p = hrow * 64 + mt * 32 + row;
            c1p[((long)(b * 4096 + p)) * 256 + oc] = splitpack(acc[mt][r] + bias);
        }
    }
}

// ---------- tiny MLP chain: sum gap partials, c2, c3 -> scale, ga, n_g ----------
__global__ __launch_bounds__(256) void k_mlp(const float* __restrict__ gpart,
                                             const float* __restrict__ b1,
                                             const float* __restrict__ w2, const float* __restrict__ b2,
                                             const float* __restrict__ w3, const float* __restrict__ b3,
                                             float* __restrict__ scale, float* __restrict__ ga,
                                             float* __restrict__ n_g) {
    int b = blockIdx.x, tid = threadIdx.x;
    __shared__ float gs[256], c2s[256], red[4];
    float g = 0.f;
#pragma unroll 8
    for (int i = 0; i < 64; ++i) g += gpart[(b * 64 + i) * 256 + tid];
    gs[tid] = g * (1.f / 4096.f) + b1[tid];
    __syncthreads();
    {
        const float4* wr = (const float4*)(w2 + tid * 256);
        float a = b2[tid];
#pragma unroll 8
        for (int c4 = 0; c4 < 64; c4++) {
            float4 wv = wr[c4];
            a += wv.x * gs[c4*4] + wv.y * gs[c4*4+1] + wv.z * gs[c4*4+2] + wv.w * gs[c4*4+3];
        }
        c2s[tid] = a;
    }
    __syncthreads();
    float a3 = b3[tid];
    {
        const float4* wr = (const float4*)(w3 + tid * 256);
#pragma unroll 8
        for (int c4 = 0; c4 < 64; c4++) {
            float4 wv = wr[c4];
            a3 += wv.x * c2s[c4*4] + wv.y * c2s[c4*4+1] + wv.z * c2s[c4*4+2] + wv.w * c2s[c4*4+3];
        }
    }
    float s1 = 1.f + a3;
    float g2 = gs[tid] * s1;
    scale[b * 256 + tid] = s1;
    ga[b * 256 + tid] = g2 * s1;
    float r = g2 * g2;
    for (int off = 32; off; off >>= 1) r += __shfl_down(r, off);
    if ((tid & 63) == 0) red[tid >> 6] = r;
    __syncthreads();
    if (tid == 0) n_g[b] = fmaxf(sqrtf(red[0] + red[1] + red[2] + red[3]), EPSF);
}

// ---------- cos -> r1[b][p], packed NHWC reads, 32-lane reduce per pixel ----------
__global__ __launch_bounds__(256) void k_cos(
        const uint32_t* __restrict__ c1p,
        const float* __restrict__ scale, const float* __restrict__ ga,
        const float* __restrict__ n_g, float* __restrict__ r1) {
    const int bx = blockIdx.x;                 // 1024 = b16 * pt64
    const int pt = bx & 63, b = bx >> 6;
    const int tid = threadIdx.x;
    const int lane = tid & 63, wv = tid >> 6;
    const int half = lane >> 5, l31 = lane & 31;
    float ga8[8], sc8[8];
#pragma unroll
    for (int q = 0; q < 8; ++q) {
        ga8[q] = ga[b * 256 + l31 * 8 + q];
        sc8[q] = scale[b * 256 + l31 * 8 + q];
    }
    const float ng = n_g[b];
#pragma unroll
    for (int pp = 0; pp < 8; ++pp) {
        const int p = pt * 64 + wv * 16 + pp * 2 + half;
        const uint32_t* base = c1p + ((long)(b * 4096 + p)) * 256 + l31 * 8;
        uint4 a = *(const uint4*)base;
        uint4 bq = *(const uint4*)(base + 4);
        uint32_t pk[8] = {a.x, a.y, a.z, a.w, bq.x, bq.y, bq.z, bq.w};
        float num = 0.f, den = 0.f;
#pragma unroll
        for (int q = 0; q < 8; ++q) {
            const float v = unpackf(pk[q]);
            num += ga8[q] * v;
            const float t = sc8[q] * v;
            den += t * t;
        }
#pragma unroll
        for (int off = 1; off <= 16; off <<= 1) {
            num += __shfl_xor(num, off);
            den += __shfl_xor(den, off);
        }
        if (l31 == 0) {
            float na = fmaxf(sqrtf(den), EPSF);
            r1[b * 4096 + p] = num / (ng * na);
        }
    }
}

// ---------- U-factor: Uf[b'][pr*256+k] = sum_o w4[o][k]*r1[b'][pr*256+o]; Dpart[b'*16+pr] ----------
__global__ __launch_bounds__(256) void k_u(const float* __restrict__ r1,
                                           const float* __restrict__ w4,
                                           const float* __restrict__ b4,
                                           float* __restrict__ Uf, float* __restrict__ Dpart) {
    const int g = blockIdx.x;                  // 256 = b'16 * pr16
    const int tid = threadIdx.x;
    __shared__ float rs[256], red[4];
    rs[tid] = r1[(g >> 4) * 4096 + (g & 15) * 256 + tid];
    __syncthreads();
    float a = 0.f;
#pragma unroll 8
    for (int o = 0; o < 256; ++o) a += rs[o] * w4[o * 256 + tid];
    Uf[(g >> 4) * 4096 + (g & 15) * 256 + tid] = a;
    float d = b4[tid] * rs[tid];
    for (int off = 32; off; off >>= 1) d += __shfl_down(d, off);
    if ((tid & 63) == 0) red[tid >> 6] = d;
    __syncthreads();
    if (tid == 0) Dpart[g] = red[0] + red[1] + red[2] + red[3];
}

// ---------- t[b][i][b'] = sum_jj c1s_flat[b][i][jj] * Uf[b'][jj] + D[b'] ----------
// A-row i = 16 consecutive NHWC pixels of c1p (unpack + *scale[k] on stage).
__global__ __launch_bounds__(256) void k_t2(const uint32_t* __restrict__ c1p,
                                            const float* __restrict__ Uf,
                                            const float* __restrict__ scale,
                                            const float* __restrict__ Dpart,
                                            float* __restrict__ tmat) {
    __shared__ float Ac[16][256];
    __shared__ float Bc[16][260];
    __shared__ float scs[256];
    const int bx = blockIdx.x;                 // 256 = b16 * it16
    const int b = bx >> 4, it = bx & 15;
    const int tid = threadIdx.x;
    const int il = tid >> 4, bp = tid & 15;
    scs[tid] = scale[b * 256 + tid];
    float acc = 0.f;
    for (int jc = 0; jc < 16; ++jc) {          // chunk: pr = jc, k in [0,256)
        __syncthreads();
#pragma unroll
        for (int q = 0; q < 4; ++q) {
            const int f4i = tid + q * 256;
            const int row = f4i >> 6, col4 = f4i & 63;
            uint4 u = *(const uint4*)(c1p +
                ((long)(b * 4096 + it * 256 + row * 16 + jc)) * 256 + col4 * 4);
            Ac[row][col4 * 4 + 0] = unpackf(u.x) * scs[col4 * 4 + 0];
            Ac[row][col4 * 4 + 1] = unpackf(u.y) * scs[col4 * 4 + 1];
            Ac[row][col4 * 4 + 2] = unpackf(u.z) * scs[col4 * 4 + 2];
            Ac[row][col4 * 4 + 3] = unpackf(u.w) * scs[col4 * 4 + 3];
            *(float4*)&Bc[row][col4 * 4] =
                *(const float4*)(Uf + (long)row * 4096 + jc * 256 + col4 * 4);
        }
        __syncthreads();
#pragma unroll 8
        for (int j = 0; j < 256; j += 4) {
            float4 a4  = *(const float4*)&Ac[il][j];
            float4 b4v = *(const float4*)&Bc[bp][j];
            acc += a4.x * b4v.x + a4.y * b4v.y + a4.z * b4v.z + a4.w * b4v.w;
        }
    }
    float D = 0.f;
#pragma unroll
    for (int pr = 0; pr < 16; ++pr) D += Dpart[bp * 16 + pr];
    tmat[((b * 256) + it * 16 + il) * 16 + bp] = acc + D;
}

// ---------- m2[b][i][p] = sum_b' t[b][i][b'] * r1[b'][p]  (writes d_out) ----------
__global__ __launch_bounds__(256) void k_m2(const float* __restrict__ tmat,
                                            const float* __restrict__ r1,
                                            float* __restrict__ outb) {
    __shared__ float r1s[16][512];
    __shared__ float ts[256];
    int bx = blockIdx.x;
    int b = bx >> 7, it = (bx >> 3) & 15, pc = bx & 7;
    int tid = threadIdx.x;
    ts[tid] = tmat[(b * 256 + it * 16) * 16 + tid];
#pragma unroll
    for (int k = 0; k < 8; k++) {
        int f4i = tid + k * 256;
        int row = f4i >> 7, col = f4i & 127;
        *(float4*)&r1s[row][col * 4] = *(const float4*)(r1 + ((long)row << 12) + pc * 512 + col * 4);
    }
    __syncthreads();
    for (int il = 0; il < 16; il++) {
        float tv[16];
#pragma unroll
        for (int bp = 0; bp < 16; bp++) tv[bp] = ts[il * 16 + bp];
#pragma unroll
        for (int k = 0; k < 2; k++) {
            int p = k * 256 + tid;
            float s = 0.f;
#pragma unroll
            for (int bp = 0; bp < 16; bp++) s += tv[bp] * r1s[bp][p];
            outb[((long)b << 20) + ((long)(it * 16 + il) << 12) + pc * 512 + p] = s;
        }
    }
}

extern "C" void kernel_launch(void* const* d_in, const int* in_sizes, int n_in,
                              void* d_out, int out_size, void* d_ws, size_t ws_size,
                              hipStream_t stream) {
    const float* x  = (const float*)d_in[0];
    const float* w1 = (const float*)d_in[1];
    const float* b1 = (const float*)d_in[2];
    const float* w2 = (const float*)d_in[3];
    const float* b2 = (const float*)d_in[4];
    const float* w3 = (const float*)d_in[5];
    const float* b3 = (const float*)d_in[6];
    const float* w4 = (const float*)d_in[7];
    const float* b4 = (const float*)d_in[8];
    float* out = (float*)d_out;

    // xp planes live in d_out's first 32MB (dead before k_m2 overwrites d_out)
    unsigned short* xph = (unsigned short*)d_out;          // 16 MB
    unsigned short* xpl = xph + 8388608L;                  // 16 MB

    char* p = (char*)d_ws;
    uint32_t* c1p = (uint32_t*)p;  p += 16777216L * 4;     // 64 MB packed hi|lo
    short* Bh  = (short*)p;  p += 294912L * 2;
    short* Bl  = (short*)p;  p += 294912L * 2;
    float* gpart = (float*)p; p += 262144L * 4;
    float* scale = (float*)p; p += 4096L * 4;
    float* ga    = (float*)p; p += 4096L * 4;
    float* n_g   = (float*)p; p += 16L * 4;
    float* r1    = (float*)p; p += 65536L * 4;
    float* tmat  = (float*)p; p += 65536L * 4;
    float* Uf    = (float*)p; p += 65536L * 4;
    float* Dpart = (float*)p; p += 256L * 4;

    k_xpack <<<4096, 256, 0, stream>>>(x, xph, xpl);
    k_wpack <<<1152, 256, 0, stream>>>(w1, Bh, Bl);
    k_conv1 <<<1024, 512, 0, stream>>>(xph, xpl, Bh, Bl, b1, c1p, gpart);
    k_mlp   <<<16,   256, 0, stream>>>(gpart, b1, w2, b2, w3, b3, scale, ga, n_g);
    k_cos   <<<1024, 256, 0, stream>>>(c1p, scale, ga, n_g, r1);
    k_u     <<<256,  256, 0, stream>>>(r1, w4, b4, Uf, Dpart);
    k_t2    <<<256,  256, 0, stream>>>(c1p, Uf, scale, Dpart, tmat);
    k_m2    <<<2048, 256, 0, stream>>>(tmat, r1, out);
}